// Round 9
// baseline (305.981 us; speedup 1.0000x reference)
//
#include <hip/hip_runtime.h>
#include <hip/hip_bf16.h>

#define DM 1024
#define NH 16
#define DH 64
#define BB 4
#define SS 2048
#define MROWS (BB*SS)   // 8192

typedef unsigned short u16;
typedef short bf16x8 __attribute__((ext_vector_type(8)));
typedef short bf16x4 __attribute__((ext_vector_type(4)));
typedef float f32x4 __attribute__((ext_vector_type(4)));
typedef unsigned uintx2 __attribute__((ext_vector_type(2)));

#define MFMA16(a, b, c) __builtin_amdgcn_mfma_f32_16x16x32_bf16((a), (b), (c), 0, 0, 0)
#define MFMA16K16(a, b, c) __builtin_amdgcn_mfma_f32_16x16x16bf16_1k((a), (b), (c), 0, 0, 0)

__device__ __forceinline__ u16 f2bf(float f) {
  union { float f; unsigned u; } v; v.f = f;
  unsigned u = v.u;
  return (u16)((u + 0x7fffu + ((u >> 16) & 1u)) >> 16);
}

// pack two floats -> u32 of two RNE bf16 (lo = a, hi = b)
__device__ __forceinline__ unsigned pack2bf(float a, float b) {
  __hip_bfloat162 h = __float22bfloat162_rn(make_float2(a, b));
  unsigned u;
  __builtin_memcpy(&u, &h, 4);
  return u;
}

__device__ __forceinline__ bf16x8 ld_bf8(const u16* p) {
  return *(const bf16x8*)p;
}

// -------- merged prep: x cvt (blocks 0..8191) + W transpose (8192..12287) --
__global__ __launch_bounds__(256) void k_prep(const float* __restrict__ x,
                                              u16* __restrict__ xb,
                                              const float* __restrict__ Wq,
                                              const float* __restrict__ Wk,
                                              const float* __restrict__ Wv,
                                              const float* __restrict__ Wo,
                                              u16* __restrict__ Wt) {
  int bid = blockIdx.x, tid = threadIdx.x;
  if (bid < 8192) {
    int i = (bid * 256 + tid) * 4;
    float4 v = *(const float4*)(x + i);
    ushort4 o;
    o.x = f2bf(v.x); o.y = f2bf(v.y); o.z = f2bf(v.z); o.w = f2bf(v.w);
    *(ushort4*)(xb + i) = o;
    return;
  }
  __shared__ float t[32][33];
  int b2 = bid - 8192;                 // 0..4095
  int k0 = (b2 & 31) * 32;
  int yy = b2 >> 5;                    // 0..127
  int seg = yy >> 5;
  int n0 = (yy & 31) * 32;
  const float* W = seg == 0 ? Wq : seg == 1 ? Wk : seg == 2 ? Wv : Wo;
  int tx = tid & 31, ty0 = (tid >> 5) * 4;
#pragma unroll
  for (int i = 0; i < 4; ++i)
    t[ty0 + i][tx] = W[(size_t)(k0 + ty0 + i) * DM + n0 + tx];
  __syncthreads();
#pragma unroll
  for (int i = 0; i < 4; ++i)
    Wt[(size_t)(seg * DM + n0 + ty0 + i) * DM + k0 + tx] = f2bf(t[tx][ty0 + i]);
}

// ---------------- GEMM (128-tile, out-proj only): C = A * Bt^T + bias -----
__global__ __launch_bounds__(256) void k_gemm(
    const u16* __restrict__ A, const u16* __restrict__ Bt,
    int M, int N, int K,
    const float* __restrict__ b0,
    float* __restrict__ of) {
  __shared__ __align__(16) u16 As[128 * 32];
  __shared__ __align__(16) u16 Bs[128 * 32];
  int tid = threadIdx.x;
  int wave = tid >> 6, lane = tid & 63, quad = lane >> 4, l16 = lane & 15;
  int bm = blockIdx.x * 128, bn = blockIdx.y * 128;
  int wr = (wave >> 1) * 64, wc = (wave & 1) * 64;
  f32x4 acc[4][4] = {};

  const u16* ga = A + (size_t)(bm + wave * 32 + (lane >> 2)) * K + (lane & 3) * 8;
  const u16* gb = Bt + (size_t)(bn + wave * 32 + (lane >> 2)) * K + (lane & 3) * 8;
  u16* lda = &As[wave * 1024];
  u16* ldb = &Bs[wave * 1024];

  for (int k0 = 0; k0 < K; k0 += 32) {
#pragma unroll
    for (int i = 0; i < 2; ++i) {
      __builtin_amdgcn_global_load_lds(
          (const __attribute__((address_space(1))) void*)(ga + (size_t)i * 16 * K + k0),
          (__attribute__((address_space(3))) void*)(lda + i * 512), 16, 0, 0);
      __builtin_amdgcn_global_load_lds(
          (const __attribute__((address_space(1))) void*)(gb + (size_t)i * 16 * K + k0),
          (__attribute__((address_space(3))) void*)(ldb + i * 512), 16, 0, 0);
    }
    __syncthreads();
    bf16x8 af[4], bfr[4];
#pragma unroll
    for (int mi = 0; mi < 4; ++mi)
      af[mi] = *(const bf16x8*)(&As[(wr + mi * 16 + l16) * 32 + quad * 8]);
#pragma unroll
    for (int ni = 0; ni < 4; ++ni)
      bfr[ni] = *(const bf16x8*)(&Bs[(wc + ni * 16 + l16) * 32 + quad * 8]);
#pragma unroll
    for (int mi = 0; mi < 4; ++mi)
#pragma unroll
      for (int ni = 0; ni < 4; ++ni)
        acc[mi][ni] = MFMA16(af[mi], bfr[ni], acc[mi][ni]);
    __syncthreads();
  }

#pragma unroll
  for (int mi = 0; mi < 4; ++mi)
#pragma unroll
    for (int ni = 0; ni < 4; ++ni)
#pragma unroll
      for (int r = 0; r < 4; ++r) {
        int row = bm + wr + mi * 16 + quad * 4 + r;
        int col = bn + wc + ni * 16 + l16;
        of[(size_t)row * N + col] = acc[mi][ni][r] + b0[col];
      }
}

// ---------------- QKV GEMM: 256x256, BK=64, 8 waves, 8-PHASE schedule -----
// R15 = R14 with the staging slack fixed. R14 counters: MfmaUtil 23%,
// VALUBusy 11.5% -> CU ~65% idle = latency-stalled. Slack audit of R14:
// A02(t+1) issued ph2(t), required complete at W1 end-ph3(t) -> ~350 cyc
// slack vs ~900 cyc HBM/L2-miss latency (8MB/XCD working set misses L2).
// Guaranteed vmcnt stall every tile, amplified by the 8-wave barrier.
// FIX: issue ALL 8 next-tile loads at phase 0 -> slack >= 3.5 phases for
// B01/B23/A02 and ~5.5 phases for A13, all > miss latency.
// Waits (FIFO audit): W1 end-ph3(t): outstanding = batch(t+1)[8], need
// first 6 -> vmcnt(2). W2 end-ph1(t): outstanding = A13(t)[2] +
// batch(t+1)[8] = 10, need A13(t) -> vmcnt(8). Last tile: vmcnt(0).
// WAR: batch(t+1) writes buf[(t+1)&1]; tile t reads buf[t&1]; buf[(t+1)&1]
// readers (tile t-1) done at boundary barrier. Math order unchanged.
__global__ __launch_bounds__(512, 2) void k_gemm3(
    const u16* __restrict__ A, const u16* __restrict__ Bt,
    const float* __restrict__ b0, const float* __restrict__ b1,
    const float* __restrict__ b2,
    u16* __restrict__ oq, u16* __restrict__ ok, u16* __restrict__ ov) {
  __shared__ __align__(16) u16 As[2][256][64];  // 64 KB
  __shared__ __align__(16) u16 Bs[2][256][64];  // 64 KB
  const int K = DM;
  int tid = threadIdx.x;
  int wave = tid >> 6, lane = tid & 63, quad = lane >> 4, l16 = lane & 15;
  int wr = wave >> 2, wc = wave & 3;
  // XCD swizzle (bijective over 384): g -> (xcd, idx); bx = xcd*4 + idx/12.
  int g = blockIdx.x + 32 * blockIdx.y;
  int xcd = g & 7, idx = g >> 3;
  int bxp = xcd * 4 + idx / 12;
  int byp = idx % 12;
  int bm = bxp * 256, bn = byp * 256;

  f32x4 acc[8][4] = {};

  // ---- staging addresses (source carries the XOR swizzle) ----
  int srow = wave * 8 + (lane >> 3);               // 0..63 (+ chunk*64)
  int scol = ((lane & 7) ^ (lane >> 3)) * 8;       // swizzled source col
  const u16* ga = A + (size_t)(bm + srow) * K + scol;
  const u16* gb = Bt + (size_t)(bn + srow) * K + scol;
  u16* aw0 = &As[0][wave * 8][0];
  u16* aw1 = &As[1][wave * 8][0];
  u16* bw0 = &Bs[0][wave * 8][0];
  u16* bw1 = &Bs[1][wave * 8][0];

  // ---- read-side frag base pointers (phys block = logical ^ (row&7)) ----
  int e7 = l16 & 7;
  const u16* aP00 = &As[0][wr * 128 + l16][0] + ((quad) ^ e7) * 8;
  const u16* aP01 = &As[0][wr * 128 + l16][0] + ((4 + quad) ^ e7) * 8;
  const u16* aP10 = &As[1][wr * 128 + l16][0] + ((quad) ^ e7) * 8;
  const u16* aP11 = &As[1][wr * 128 + l16][0] + ((4 + quad) ^ e7) * 8;
  const u16* bP00 = &Bs[0][wc * 64 + l16][0] + ((quad) ^ e7) * 8;
  const u16* bP01 = &Bs[0][wc * 64 + l16][0] + ((4 + quad) ^ e7) * 8;
  const u16* bP10 = &Bs[1][wc * 64 + l16][0] + ((quad) ^ e7) * 8;
  const u16* bP11 = &Bs[1][wc * 64 + l16][0] + ((4 + quad) ^ e7) * 8;

#define SBAR()                            \
  {                                       \
    asm volatile("" ::: "memory");        \
    __builtin_amdgcn_s_barrier();         \
    asm volatile("" ::: "memory");        \
  }

#define GLD(gp, lp)                                                \
  __builtin_amdgcn_global_load_lds(                                \
      (const __attribute__((address_space(1))) void*)(gp),         \
      (__attribute__((address_space(3))) void*)(lp), 16, 0, 0)

// issue order = B01, B23, A02, A13 (oldest-first for the vmcnt counts)
#define STG_ALL(TI, NB)                                            \
  {                                                                \
    GLD(gb + (size_t)(TI) * 64, bw##NB);                           \
    GLD(gb + (size_t)64 * K + (size_t)(TI) * 64, bw##NB + 4096);   \
    GLD(gb + (size_t)128 * K + (size_t)(TI) * 64, bw##NB + 8192);  \
    GLD(gb + (size_t)192 * K + (size_t)(TI) * 64, bw##NB + 12288); \
    GLD(ga + (size_t)(TI) * 64, aw##NB);                           \
    GLD(ga + (size_t)128 * K + (size_t)(TI) * 64, aw##NB + 8192);  \
    GLD(ga + (size_t)64 * K + (size_t)(TI) * 64, aw##NB + 4096);   \
    GLD(ga + (size_t)192 * K + (size_t)(TI) * 64, aw##NB + 12288); \
  }

#define MM2(M0, M1)                                                \
  _Pragma("unroll") for (int n = 0; n < 4; ++n) {                  \
    acc[M0][n] = MFMA16(afA0, bfr[n][0], acc[M0][n]);              \
    acc[M0][n] = MFMA16(afA1, bfr[n][1], acc[M0][n]);              \
    acc[M1][n] = MFMA16(afB0, bfr[n][0], acc[M1][n]);              \
    acc[M1][n] = MFMA16(afB1, bfr[n][1], acc[M1][n]);              \
  }

#define TILE(T, BUF, NB, DOSTAGE)                                             \
  {                                                                           \
    bf16x8 bfr[4][2];                                                         \
    _Pragma("unroll") for (int n = 0; n < 4; ++n) {                           \
      bfr[n][0] = *(const bf16x8*)(bP##BUF##0 + n * 1024);                    \
      bfr[n][1] = *(const bf16x8*)(bP##BUF##1 + n * 1024);                    \
    }                                                                         \
    bf16x8 afA0 = *(const bf16x8*)(aP##BUF##0 + 0 * 1024);                    \
    bf16x8 afA1 = *(const bf16x8*)(aP##BUF##1 + 0 * 1024);                    \
    bf16x8 afB0 = *(const bf16x8*)(aP##BUF##0 + 1 * 1024);                    \
    bf16x8 afB1 = *(const bf16x8*)(aP##BUF##1 + 1 * 1024);                    \
    if (DOSTAGE) STG_ALL((T) + 1, NB);                                        \
    SBAR();                                                                   \
    __builtin_amdgcn_s_setprio(1);                                            \
    MM2(0, 1);                                                                \
    __builtin_amdgcn_s_setprio(0);                                            \
    SBAR();                                                                   \
    afA0 = *(const bf16x8*)(aP##BUF##0 + 2 * 1024);                           \
    afA1 = *(const bf16x8*)(aP##BUF##1 + 2 * 1024);                           \
    afB0 = *(const bf16x8*)(aP##BUF##0 + 3 * 1024);                           \
    afB1 = *(const bf16x8*)(aP##BUF##1 + 3 * 1024);                           \
    SBAR();                                                                   \
    __builtin_amdgcn_s_setprio(1);                                            \
    MM2(2, 3);                                                                \
    __builtin_amdgcn_s_setprio(0);                                            \
    if (DOSTAGE) {                                                            \
      asm volatile("s_waitcnt vmcnt(8)" ::: "memory");                        \
    } else {                                                                  \
      asm volatile("s_waitcnt vmcnt(0)" ::: "memory");                        \
    }                                                                         \
    SBAR();                                                                   \
    afA0 = *(const bf16x8*)(aP##BUF##0 + 4 * 1024);                           \
    afA1 = *(const bf16x8*)(aP##BUF##1 + 4 * 1024);                           \
    afB0 = *(const bf16x8*)(aP##BUF##0 + 5 * 1024);                           \
    afB1 = *(const bf16x8*)(aP##BUF##1 + 5 * 1024);                           \
    SBAR();                                                                   \
    __builtin_amdgcn_s_setprio(1);                                            \
    MM2(4, 5);                                                                \
    __builtin_amdgcn_s_setprio(0);                                            \
    SBAR();                                                                   \
    afA0 = *(const bf16x8*)(aP##BUF##0 + 6 * 1024);                           \
    afA1 = *(const bf16x8*)(aP##BUF##1 + 6 * 1024);                           \
    afB0 = *(const bf16x8*)(aP##BUF##0 + 7 * 1024);                           \
    afB1 = *(const bf16x8*)(aP##BUF##1 + 7 * 1024);                           \
    SBAR();                                                                   \
    __builtin_amdgcn_s_setprio(1);                                            \
    MM2(6, 7);                                                                \
    __builtin_amdgcn_s_setprio(0);                                            \
    if (DOSTAGE) {                                                            \
      asm volatile("s_waitcnt vmcnt(2)" ::: "memory");                        \
    }                                                                         \
    SBAR();                                                                   \
  }

  STG_ALL(0, 0);
  asm volatile("s_waitcnt vmcnt(2)" ::: "memory");
  SBAR();

#pragma unroll 1
  for (int tt = 0; tt < 7; ++tt) {
    int t0 = tt * 2;
    TILE(t0, 0, 1, 1);
    TILE(t0 + 1, 1, 0, 1);
  }
  TILE(14, 0, 1, 1);
  TILE(15, 1, 0, 0);

#undef TILE
#undef MM2
#undef STG_ALL
#undef GLD
#undef SBAR

  // ---- epilogue: bias + QKV scatter (BN=256 divides the 1024 segments) ---
  int seg = bn >> 10;
  const float* bia = seg == 0 ? b0 : seg == 1 ? b1 : b2;
  int cb = bn & 1023;
  if (seg == 2) {
#pragma unroll
    for (int m = 0; m < 8; ++m)
#pragma unroll
      for (int n = 0; n < 4; ++n) {
        int row = bm + wr * 128 + m * 16 + quad * 4;
        int col = cb + wc * 64 + n * 16 + l16;
        float bv_ = bia[col];
        int bb2 = row >> 11, s = row & 2047, hh = col >> 6, dh = col & 63;
        ushort4 o4;
        o4.x = f2bf(acc[m][n][0] + bv_);
        o4.y = f2bf(acc[m][n][1] + bv_);
        o4.z = f2bf(acc[m][n][2] + bv_);
        o4.w = f2bf(acc[m][n][3] + bv_);
        *(ushort4*)(&ov[(((size_t)bb2 * NH + hh) * DH + dh) * SS + s]) = o4;
      }
  } else {
    u16* o = seg == 0 ? oq : ok;
    float sc = seg == 0 ? (0.125f * 1.44269504f) : 1.0f;
#pragma unroll
    for (int m = 0; m < 8; ++m)
#pragma unroll
      for (int n = 0; n < 4; ++n)
#pragma unroll
        for (int r = 0; r < 4; ++r) {
          int row = bm + wr * 128 + m * 16 + quad * 4 + r;
          int col = cb + wc * 64 + n * 16 + l16;
          float v = (acc[m][n][r] + bia[col]) * sc;
          int bb2 = row >> 11, s = row & 2047, hh = col >> 6, dh = col & 63;
          o[((((size_t)bb2 * NH + hh) * SS) + s) * DH + dh] = f2bf(v);
        }
  }
}

// ---------------- flash attention (R0 structure; split over batch) --------
__global__ __launch_bounds__(256) void k_attn(const u16* __restrict__ Q,
                                              const u16* __restrict__ Kg,
                                              const u16* __restrict__ VT,
                                              u16* __restrict__ ctx,
                                              int zoff) {
  __shared__ __align__(16) u16 Ks[2][64][64];
  __shared__ __align__(16) u16 Vts[2][64][64];  // [d][kv], swizzled
  int tid = threadIdx.x;
  int wave = tid >> 6, lane = tid & 63, quad = lane >> 4, l16 = lane & 15;
  int q0 = blockIdx.x * 128;
  int h = blockIdx.y, b = blockIdx.z + zoff;
  size_t bh = ((size_t)b * NH + h) * SS * DH;
  const u16* Qp = Q + bh + (size_t)(q0 + wave * 32) * DH;
  const u16* Kp = Kg + bh;
  const u16* Vp = VT + ((size_t)b * NH + h) * DH * SS;  // [Dh][S]

  // Q as B-operand fragments: B[k=d=quad*8+j][n=q=l16], 2 q-tiles
  bf16x8 qf[2][2];
#pragma unroll
  for (int qt = 0; qt < 2; ++qt) {
    qf[qt][0] = ld_bf8(Qp + (qt * 16 + l16) * DH + quad * 8);
    qf[qt][1] = ld_bf8(Qp + (qt * 16 + l16) * DH + 32 + quad * 8);
  }

  f32x4 Ot[4][2] = {};           // [d-tile][q-tile], O^T C-layout
  float lrun[2] = {0.0f, 0.0f};  // per-lane partial sums (q = l16)

  // ---- staging constants (global side carries the swizzle) ----
  int lrow = lane >> 3;            // 0..7 (row within 8-row DMA chunk)
  int lcb = (lane & 7) ^ lrow;     // swizzled global col-block
  const u16* kdma[2];
  const u16* vdma[2];
  u16* kl[2];
  u16* vl[2];
#pragma unroll
  for (int i = 0; i < 2; ++i) {
    int chunk = wave * 2 + i;      // 0..7, 8 rows each
    kdma[i] = Kp + (size_t)(chunk * 8 + lrow) * DH + lcb * 8;
    vdma[i] = Vp + (size_t)(chunk * 8 + lrow) * SS + lcb * 8;
    kl[i] = &Ks[0][chunk * 8][0];
    vl[i] = &Vts[0][chunk * 8][0];
  }

  // ---- hoisted frag pointers (loop addressing = base + literal) ----
  int e7 = l16 & 7, qh = quad >> 1, qp = quad & 1;
  const u16* kfr0 = &Ks[0][l16][(quad ^ e7) * 8];        // d-blocks 0..3
  const u16* kfr1 = &Ks[0][l16][((quad + 4) ^ e7) * 8];  // d-blocks 4..7
  const u16* vfr[4];
#pragma unroll
  for (int c = 0; c < 4; ++c)
    vfr[c] = &Vts[0][l16][((2 * c + qh) ^ e7) * 8 + qp * 4];

  // ---- prestage tile kv=0 into buffer 0 ----
#pragma unroll
  for (int i = 0; i < 2; ++i) {
    __builtin_amdgcn_global_load_lds(
        (const __attribute__((address_space(1))) void*)kdma[i],
        (__attribute__((address_space(3))) void*)kl[i], 16, 0, 0);
    __builtin_amdgcn_global_load_lds(
        (const __attribute__((address_space(1))) void*)vdma[i],
        (__attribute__((address_space(3))) void*)vl[i], 16, 0, 0);
  }
  __syncthreads();

  int kv = 64;  // next tile to stage

#define ATTN_STEP(P)                                                          \
  {                                                                           \
    f32x4 s[2][4];                                                            \
    _Pragma("unroll") for (int t = 0; t < 4; ++t) {                           \
      bf16x8 kb0 = *(const bf16x8*)(kfr0 + (P) * 4096 + t * 1024);            \
      bf16x8 kb1 = *(const bf16x8*)(kfr1 + (P) * 4096 + t * 1024);            \
      _Pragma("unroll") for (int qt = 0; qt < 2; ++qt) {                      \
        f32x4 z = {};                                                         \
        z = MFMA16(kb0, qf[qt][0], z);                                        \
        z = MFMA16(kb1, qf[qt][1], z);                                        \
        s[qt][t] = z;                                                         \
      }                                                                       \
    }                                                                         \
    if (kv < SS) {                                                            \
      _Pragma("unroll") for (int i = 0; i < 2; ++i) {                         \
        __builtin_amdgcn_global_load_lds(                                     \
            (const __attribute__((address_space(1))) void*)(kdma[i] +         \
                                                            (size_t)kv * DH), \
            (__attribute__((address_space(3))) void*)(kl[i] +                 \
                                                      (1 - (P)) * 4096),      \
            16, 0, 0);                                                        \
        __builtin_amdgcn_global_load_lds(                                     \
            (const __attribute__((address_space(1))) void*)(vdma[i] + kv),    \
            (__attribute__((address_space(3))) void*)(vl[i] +                 \
                                                      (1 - (P)) * 4096),      \
            16, 0, 0);                                                        \
      }                                                                       \
    }                                                                         \
    bf16x4 pb[2][4];                                                          \
    _Pragma("unroll") for (int qt = 0; qt < 2; ++qt)                          \
        _Pragma("unroll") for (int t = 0; t < 4; ++t) {                       \
      unsigned u0 = __builtin_bit_cast(                                       \
          unsigned, __builtin_amdgcn_exp2f(s[qt][t][0]));                     \
      unsigned u1 = __builtin_bit_cast(                                       \
          unsigned, __builtin_amdgcn_exp2f(s[qt][t][1]));                     \
      unsigned u2 = __builtin_bit_cast(                                       \
          unsigned, __builtin_amdgcn_exp2f(s[qt][t][2]));                     \
      unsigned u3 = __builtin_bit_cast(                                       \
          unsigned, __builtin_amdgcn_exp2f(s[qt][t][3]));                     \
      unsigned w0 = __builtin_amdgcn_perm(u1, u0, 0x07060302u);               \
      unsigned w1 = __builtin_amdgcn_perm(u3, u2, 0x07060302u);               \
      lrun[qt] += __builtin_bit_cast(float, w0 << 16) +                       \
                  __builtin_bit_cast(float, w0 & 0xffff0000u) +               \
                  __builtin_bit_cast(float, w1 << 16) +                       \
                  __builtin_bit_cast(float, w1 & 0xffff0000u);                \
      uintx2 w;                                                               \
      w[0] = w0;                                                              \
      w[1] = w1;                                                              \
      pb[qt][t] = __builtin_bit_cast(bf16x4, w);                              \
    }                                                                         \
    _Pragma("unroll") for (int c = 0; c < 4; ++c)                             \
        _Pragma("unroll") for (int dt = 0; dt < 4; ++dt) {                    \
      bf16x4 va = *(const bf16x4*)(vfr[c] + (P) * 4096 + dt * 1024);          \
      _Pragma("unroll") for (int qt = 0; qt < 2; ++qt)                        \
          Ot[dt][qt] = MFMA16K16(va, pb[qt][c], Ot[dt][qt]);                  \
    }                                                                         \
    __syncthreads();                                                          \
    kv += 64;                                                                 \
  }

  for (int it = 0; it < SS / 128; ++it) {
    ATTN_STEP(0);
    ATTN_STEP(1);
  }
#undef ATTN_STEP

  // final normalizer: lanes {l16, +16, +32, +48} hold q=l16 partials
  float inv[2];
#pragma unroll
  for (int qt = 0; qt < 2; ++qt) {
    float l = lrun[qt];
    l += __shfl_xor(l, 16);
    l += __shfl_xor(l, 32);
    inv[qt] = 1.0f / l;
  }

  // write O^T: per lane q = l16 (fixed), d = dt*16 + quad*4 + r (contiguous)
#pragma unroll
  for (int qt = 0; qt < 2; ++qt) {
    int q = q0 + wave * 32 + qt * 16 + l16;
    size_t ob = ((size_t)b * SS + q) * DM + h * DH;
#pragma unroll
    for (int dt = 0; dt < 4; ++dt) {
      uintx2 o;
      o[0] = pack2bf(Ot[dt][qt][0] * inv[qt], Ot[dt][qt][1] * inv[qt]);
      o[1] = pack2bf(Ot[dt][qt][2] * inv[qt], Ot[dt][qt][3] * inv[qt]);
      *(uintx2*)(&ctx[ob + dt * 16 + quad * 4]) = o;
    }
  }
}

extern "C" void kernel_launch(void* const* d_in, const int* in_sizes, int n_in,
                              void* d_out, int out_size, void* d_ws, size_t ws_size,
                              hipStream_t stream) {
  const float* x  = (const float*)d_in[0];
  const float* Wq = (const float*)d_in[1];
  const float* bq = (const float*)d_in[2];
  const float* Wk = (const float*)d_in[3];
  const float* bk = (const float*)d_in[4];
  const float* Wv = (const float*)d_in[5];
  const float* bv = (const float*)d_in[6];
  const float* Wo = (const float*)d_in[7];
  const float* bo = (const float*)d_in[8];
  float* out = (float*)d_out;

  char* ws = (char*)d_ws;
  u16* xb = (u16*)(ws);                        // 16 MB  [8192,1024] bf16
  u16* Wt = (u16*)(ws + (16u << 20));          //  8 MB  [4096,1024] bf16
  u16* Qb = (u16*)(ws + (24u << 20));          // 16 MB  [B,H,S,Dh] (pre-scaled)
  u16* Kb = (u16*)(ws + (40u << 20));          // 16 MB  [B,H,S,Dh]
  u16* VT = (u16*)(ws + (56u << 20));          // 16 MB  [B,H,Dh,S]
  u16* Cb = (u16*)(ws + (72u << 20));          // 16 MB  [B,S,D] bf16 ctx

  k_prep<<<8192 + 4096, 256, 0, stream>>>(x, xb, Wq, Wk, Wv, Wo, Wt);
  k_gemm3<<<dim3(MROWS / 256, 12), 512, 0, stream>>>(
      xb, Wt, bq, bk, bv, Qb, Kb, VT);
  k_attn<<<dim3(SS / 128, NH, 2), 256, 0, stream>>>(Qb, Kb, VT, Cb, 0);
  k_attn<<<dim3(SS / 128, NH, 2), 256, 0, stream>>>(Qb, Kb, VT, Cb, 2);
  k_gemm<<<dim3(MROWS / 128, 8), 256, 0, stream>>>(
      Cb, Wt + (size_t)3 * DM * DM, MROWS, DM, DM, bo, out);
}

// Round 10
// 291.828 us; speedup vs baseline: 1.0485x; 1.0485x over previous
//
#include <hip/hip_runtime.h>
#include <hip/hip_bf16.h>

#define DM 1024
#define NH 16
#define DH 64
#define BB 4
#define SS 2048
#define MROWS (BB*SS)   // 8192

typedef unsigned short u16;
typedef short bf16x8 __attribute__((ext_vector_type(8)));
typedef short bf16x4 __attribute__((ext_vector_type(4)));
typedef float f32x4 __attribute__((ext_vector_type(4)));
typedef unsigned uintx2 __attribute__((ext_vector_type(2)));

#define MFMA16(a, b, c) __builtin_amdgcn_mfma_f32_16x16x32_bf16((a), (b), (c), 0, 0, 0)
#define MFMA16K16(a, b, c) __builtin_amdgcn_mfma_f32_16x16x16bf16_1k((a), (b), (c), 0, 0, 0)

__device__ __forceinline__ u16 f2bf(float f) {
  union { float f; unsigned u; } v; v.f = f;
  unsigned u = v.u;
  return (u16)((u + 0x7fffu + ((u >> 16) & 1u)) >> 16);
}

// pack two floats -> u32 of two RNE bf16 (lo = a, hi = b)
__device__ __forceinline__ unsigned pack2bf(float a, float b) {
  __hip_bfloat162 h = __float22bfloat162_rn(make_float2(a, b));
  unsigned u;
  __builtin_memcpy(&u, &h, 4);
  return u;
}

__device__ __forceinline__ bf16x8 ld_bf8(const u16* p) {
  return *(const bf16x8*)p;
}

// -------- merged prep: x cvt (blocks 0..8191) + W transpose (8192..12287) --
__global__ __launch_bounds__(256) void k_prep(const float* __restrict__ x,
                                              u16* __restrict__ xb,
                                              const float* __restrict__ Wq,
                                              const float* __restrict__ Wk,
                                              const float* __restrict__ Wv,
                                              const float* __restrict__ Wo,
                                              u16* __restrict__ Wt) {
  int bid = blockIdx.x, tid = threadIdx.x;
  if (bid < 8192) {
    int i = (bid * 256 + tid) * 4;
    float4 v = *(const float4*)(x + i);
    ushort4 o;
    o.x = f2bf(v.x); o.y = f2bf(v.y); o.z = f2bf(v.z); o.w = f2bf(v.w);
    *(ushort4*)(xb + i) = o;
    return;
  }
  __shared__ float t[32][33];
  int b2 = bid - 8192;                 // 0..4095
  int k0 = (b2 & 31) * 32;
  int yy = b2 >> 5;                    // 0..127
  int seg = yy >> 5;
  int n0 = (yy & 31) * 32;
  const float* W = seg == 0 ? Wq : seg == 1 ? Wk : seg == 2 ? Wv : Wo;
  int tx = tid & 31, ty0 = (tid >> 5) * 4;
#pragma unroll
  for (int i = 0; i < 4; ++i)
    t[ty0 + i][tx] = W[(size_t)(k0 + ty0 + i) * DM + n0 + tx];
  __syncthreads();
#pragma unroll
  for (int i = 0; i < 4; ++i)
    Wt[(size_t)(seg * DM + n0 + ty0 + i) * DM + k0 + tx] = f2bf(t[tx][ty0 + i]);
}

// ---------------- GEMM (128-tile, out-proj only): C = A * Bt^T + bias -----
__global__ __launch_bounds__(256) void k_gemm(
    const u16* __restrict__ A, const u16* __restrict__ Bt,
    int M, int N, int K,
    const float* __restrict__ b0,
    float* __restrict__ of) {
  __shared__ __align__(16) u16 As[128 * 32];
  __shared__ __align__(16) u16 Bs[128 * 32];
  int tid = threadIdx.x;
  int wave = tid >> 6, lane = tid & 63, quad = lane >> 4, l16 = lane & 15;
  int bm = blockIdx.x * 128, bn = blockIdx.y * 128;
  int wr = (wave >> 1) * 64, wc = (wave & 1) * 64;
  f32x4 acc[4][4] = {};

  const u16* ga = A + (size_t)(bm + wave * 32 + (lane >> 2)) * K + (lane & 3) * 8;
  const u16* gb = Bt + (size_t)(bn + wave * 32 + (lane >> 2)) * K + (lane & 3) * 8;
  u16* lda = &As[wave * 1024];
  u16* ldb = &Bs[wave * 1024];

  for (int k0 = 0; k0 < K; k0 += 32) {
#pragma unroll
    for (int i = 0; i < 2; ++i) {
      __builtin_amdgcn_global_load_lds(
          (const __attribute__((address_space(1))) void*)(ga + (size_t)i * 16 * K + k0),
          (__attribute__((address_space(3))) void*)(lda + i * 512), 16, 0, 0);
      __builtin_amdgcn_global_load_lds(
          (const __attribute__((address_space(1))) void*)(gb + (size_t)i * 16 * K + k0),
          (__attribute__((address_space(3))) void*)(ldb + i * 512), 16, 0, 0);
    }
    __syncthreads();
    bf16x8 af[4], bfr[4];
#pragma unroll
    for (int mi = 0; mi < 4; ++mi)
      af[mi] = *(const bf16x8*)(&As[(wr + mi * 16 + l16) * 32 + quad * 8]);
#pragma unroll
    for (int ni = 0; ni < 4; ++ni)
      bfr[ni] = *(const bf16x8*)(&Bs[(wc + ni * 16 + l16) * 32 + quad * 8]);
#pragma unroll
    for (int mi = 0; mi < 4; ++mi)
#pragma unroll
      for (int ni = 0; ni < 4; ++ni)
        acc[mi][ni] = MFMA16(af[mi], bfr[ni], acc[mi][ni]);
    __syncthreads();
  }

#pragma unroll
  for (int mi = 0; mi < 4; ++mi)
#pragma unroll
    for (int ni = 0; ni < 4; ++ni)
#pragma unroll
      for (int r = 0; r < 4; ++r) {
        int row = bm + wr + mi * 16 + quad * 4 + r;
        int col = bn + wc + ni * 16 + l16;
        of[(size_t)row * N + col] = acc[mi][ni][r] + b0[col];
      }
}

// ------- QKV GEMM: 128x256 tile, BK=64, TRIPLE-buffered, 768 wgs ---------
// R16 vs R15 (82.3us, MfmaUtil 24%): two structural fixes.
//  1. TAIL: 384 wgs was 1.5 rounds on 256 CUs (~25% idle). 128x256 tile ->
//     grid (64,12) = 768 wgs = exactly 3 rounds.
//  2. BOUNDARY DRAIN: 2 buffers forced a near-total drain of the next
//     tile's batch at each boundary. Triple buffer (48KB/tile x3 = 144KB
//     <= 160KB): tile t stages t+2 -> buf[(t+2)%3]; t+1's batch has ~2
//     tiles in flight; boundary wait = vmcnt(6) (allows t+2's whole
//     6-load batch outstanding, requires t+1's complete; batches are
//     exactly 6 -> FIFO-exact). Steady loop NEVER drains vmcnt.
// 8 waves (2m x 4n), per-wave 64x64, acc[4][4]; 2 phases/tile x 16 MFMA.
// Same XOR swizzle + math order as R12-R15 -> bitwise-identical output.
// WAR: stage into buf b at ph0 of t lands after t's start barrier; buf b's
// readers (tile t-1) finished before that barrier.
__global__ __launch_bounds__(512, 1) void k_gemm3(
    const u16* __restrict__ A, const u16* __restrict__ Bt,
    const float* __restrict__ b0, const float* __restrict__ b1,
    const float* __restrict__ b2,
    u16* __restrict__ oq, u16* __restrict__ ok, u16* __restrict__ ov) {
  __shared__ __align__(16) u16 As[3][128][64];  // 48 KB
  __shared__ __align__(16) u16 Bs[3][256][64];  // 96 KB
  const int K = DM;
  int tid = threadIdx.x;
  int wave = tid >> 6, lane = tid & 63, quad = lane >> 4, l16 = lane & 15;
  int wr = wave >> 2, wc = wave & 3;
  // XCD swizzle (bijective over 768 = 8 XCD x 96): XCD x owns bx in
  // [8x, 8x+8) across all 12 by -> 2MB A-panel set L2-resident per XCD.
  int g = blockIdx.x + 64 * blockIdx.y;
  int xcd = g & 7, idx = g >> 3;           // idx 0..95
  int bm = (xcd * 8 + (idx & 7)) * 128;
  int bn = (idx >> 3) * 256;

  f32x4 acc[4][4] = {};

  // ---- staging addresses (source carries the XOR swizzle) ----
  int srow = wave * 8 + (lane >> 3);           // 0..63 (+ j*64)
  int scol = ((lane & 7) ^ (lane >> 3)) * 8;   // swizzled source col
  const u16* ga = A + (size_t)(bm + srow) * K + scol;
  const u16* gb = Bt + (size_t)(bn + srow) * K + scol;
  u16* aw0 = &As[0][wave * 8][0];
  u16* aw1 = &As[1][wave * 8][0];
  u16* aw2 = &As[2][wave * 8][0];
  u16* bw0 = &Bs[0][wave * 8][0];
  u16* bw1 = &Bs[1][wave * 8][0];
  u16* bw2 = &Bs[2][wave * 8][0];

  // ---- read-side frag base pointers (phys block = logical ^ (row&7)) ----
  int e7 = l16 & 7;
  int blk0 = ((quad) ^ e7) * 8, blk1 = ((4 + quad) ^ e7) * 8;
  const u16* aP0_0 = &As[0][wr * 64 + l16][0] + blk0;
  const u16* aP0_1 = &As[0][wr * 64 + l16][0] + blk1;
  const u16* aP1_0 = &As[1][wr * 64 + l16][0] + blk0;
  const u16* aP1_1 = &As[1][wr * 64 + l16][0] + blk1;
  const u16* aP2_0 = &As[2][wr * 64 + l16][0] + blk0;
  const u16* aP2_1 = &As[2][wr * 64 + l16][0] + blk1;
  const u16* bP0_0 = &Bs[0][wc * 64 + l16][0] + blk0;
  const u16* bP0_1 = &Bs[0][wc * 64 + l16][0] + blk1;
  const u16* bP1_0 = &Bs[1][wc * 64 + l16][0] + blk0;
  const u16* bP1_1 = &Bs[1][wc * 64 + l16][0] + blk1;
  const u16* bP2_0 = &Bs[2][wc * 64 + l16][0] + blk0;
  const u16* bP2_1 = &Bs[2][wc * 64 + l16][0] + blk1;

#define SBAR()                            \
  {                                       \
    asm volatile("" ::: "memory");        \
    __builtin_amdgcn_s_barrier();         \
    asm volatile("" ::: "memory");        \
  }

#define GLD(gp, lp)                                                \
  __builtin_amdgcn_global_load_lds(                                \
      (const __attribute__((address_space(1))) void*)(gp),         \
      (__attribute__((address_space(3))) void*)(lp), 16, 0, 0)

// one 6-load batch for K-tile KT into buffer set SB (B: 4 chunks, A: 2)
#define STG_ALL(KT, SB)                                            \
  {                                                                \
    size_t ko = (size_t)(KT) * 64;                                 \
    GLD(gb + ko, bw##SB);                                          \
    GLD(gb + (size_t)64 * K + ko, bw##SB + 4096);                  \
    GLD(gb + (size_t)128 * K + ko, bw##SB + 8192);                 \
    GLD(gb + (size_t)192 * K + ko, bw##SB + 12288);                \
    GLD(ga + ko, aw##SB);                                          \
    GLD(ga + (size_t)64 * K + ko, aw##SB + 4096);                  \
  }

#define MM2(M0, M1)                                                \
  _Pragma("unroll") for (int n = 0; n < 4; ++n) {                  \
    acc[M0][n] = MFMA16(afA0, bfr[n][0], acc[M0][n]);              \
    acc[M0][n] = MFMA16(afA1, bfr[n][1], acc[M0][n]);              \
    acc[M1][n] = MFMA16(afB0, bfr[n][0], acc[M1][n]);              \
    acc[M1][n] = MFMA16(afB1, bfr[n][1], acc[M1][n]);              \
  }

#define VM6() asm volatile("s_waitcnt vmcnt(6)" ::: "memory")
#define VM0() asm volatile("s_waitcnt vmcnt(0)" ::: "memory")
#define VMNONE()

#define TILE(T, BUF, SB, DOSTAGE, WAITOP)                                     \
  {                                                                           \
    /* phase 0: all B frags + A m0,m1 ; stage tile T+2 */                     \
    bf16x8 bfr[4][2];                                                         \
    _Pragma("unroll") for (int n = 0; n < 4; ++n) {                           \
      bfr[n][0] = *(const bf16x8*)(bP##BUF##_0 + n * 1024);                   \
      bfr[n][1] = *(const bf16x8*)(bP##BUF##_1 + n * 1024);                   \
    }                                                                         \
    bf16x8 afA0 = *(const bf16x8*)(aP##BUF##_0 + 0 * 1024);                   \
    bf16x8 afA1 = *(const bf16x8*)(aP##BUF##_1 + 0 * 1024);                   \
    bf16x8 afB0 = *(const bf16x8*)(aP##BUF##_0 + 1 * 1024);                   \
    bf16x8 afB1 = *(const bf16x8*)(aP##BUF##_1 + 1 * 1024);                   \
    if (DOSTAGE) STG_ALL((T) + 2, SB);                                        \
    SBAR();                                                                   \
    __builtin_amdgcn_s_setprio(1);                                            \
    MM2(0, 1);                                                                \
    __builtin_amdgcn_s_setprio(0);                                            \
    SBAR();                                                                   \
    /* phase 1: A m2,m3 */                                                    \
    afA0 = *(const bf16x8*)(aP##BUF##_0 + 2 * 1024);                          \
    afA1 = *(const bf16x8*)(aP##BUF##_1 + 2 * 1024);                          \
    afB0 = *(const bf16x8*)(aP##BUF##_0 + 3 * 1024);                          \
    afB1 = *(const bf16x8*)(aP##BUF##_1 + 3 * 1024);                          \
    SBAR();                                                                   \
    __builtin_amdgcn_s_setprio(1);                                            \
    MM2(2, 3);                                                                \
    __builtin_amdgcn_s_setprio(0);                                            \
    WAITOP();                                                                 \
    SBAR();                                                                   \
  }

  // ---- prologue: stage tiles 0,1; wait tile-0 batch (allow tile-1's) ----
  STG_ALL(0, 0);
  STG_ALL(1, 1);
  VM6();
  SBAR();

#pragma unroll 1
  for (int t3 = 0; t3 < 4; ++t3) {   // tiles 0..11
    int t = t3 * 3;
    TILE(t, 0, 2, 1, VM6);
    TILE(t + 1, 1, 0, 1, VM6);
    TILE(t + 2, 2, 1, 1, VM6);
  }
  TILE(12, 0, 2, 1, VM6);
  TILE(13, 1, 0, 1, VM6);
  TILE(14, 2, 1, 0, VM0);   // drain: tile 15's batch must land
  TILE(15, 0, 1, 0, VMNONE);

#undef TILE
#undef VMNONE
#undef VM0
#undef VM6
#undef MM2
#undef STG_ALL
#undef GLD
#undef SBAR

  // ---- epilogue: bias + QKV scatter (BN=256 divides the 1024 segments) ---
  int seg = bn >> 10;
  const float* bia = seg == 0 ? b0 : seg == 1 ? b1 : b2;
  int cb = bn & 1023;
  if (seg == 2) {
#pragma unroll
    for (int m = 0; m < 4; ++m)
#pragma unroll
      for (int n = 0; n < 4; ++n) {
        int row = bm + wr * 64 + m * 16 + quad * 4;
        int col = cb + wc * 64 + n * 16 + l16;
        float bv_ = bia[col];
        int bb2 = row >> 11, s = row & 2047, hh = col >> 6, dh = col & 63;
        ushort4 o4;
        o4.x = f2bf(acc[m][n][0] + bv_);
        o4.y = f2bf(acc[m][n][1] + bv_);
        o4.z = f2bf(acc[m][n][2] + bv_);
        o4.w = f2bf(acc[m][n][3] + bv_);
        *(ushort4*)(&ov[(((size_t)bb2 * NH + hh) * DH + dh) * SS + s]) = o4;
      }
  } else {
    u16* o = seg == 0 ? oq : ok;
    float sc = seg == 0 ? (0.125f * 1.44269504f) : 1.0f;
#pragma unroll
    for (int m = 0; m < 4; ++m)
#pragma unroll
      for (int n = 0; n < 4; ++n)
#pragma unroll
        for (int r = 0; r < 4; ++r) {
          int row = bm + wr * 64 + m * 16 + quad * 4 + r;
          int col = cb + wc * 64 + n * 16 + l16;
          float v = (acc[m][n][r] + bia[col]) * sc;
          int bb2 = row >> 11, s = row & 2047, hh = col >> 6, dh = col & 63;
          o[((((size_t)bb2 * NH + hh) * SS) + s) * DH + dh] = f2bf(v);
        }
  }
}

// ---------------- flash attention (R0-exact single dispatch) --------------
// grid: (S/128, NH, BB), block 256 (4 waves, 32 q-rows each)
__global__ __launch_bounds__(256) void k_attn(const u16* __restrict__ Q,
                                              const u16* __restrict__ Kg,
                                              const u16* __restrict__ VT,
                                              u16* __restrict__ ctx) {
  __shared__ __align__(16) u16 Ks[2][64][64];
  __shared__ __align__(16) u16 Vts[2][64][64];  // [d][kv], swizzled
  int tid = threadIdx.x;
  int wave = tid >> 6, lane = tid & 63, quad = lane >> 4, l16 = lane & 15;
  int q0 = blockIdx.x * 128;
  int h = blockIdx.y, b = blockIdx.z;
  size_t bh = ((size_t)b * NH + h) * SS * DH;
  const u16* Qp = Q + bh + (size_t)(q0 + wave * 32) * DH;
  const u16* Kp = Kg + bh;
  const u16* Vp = VT + ((size_t)b * NH + h) * DH * SS;  // [Dh][S]

  // Q as B-operand fragments: B[k=d=quad*8+j][n=q=l16], 2 q-tiles
  bf16x8 qf[2][2];
#pragma unroll
  for (int qt = 0; qt < 2; ++qt) {
    qf[qt][0] = ld_bf8(Qp + (qt * 16 + l16) * DH + quad * 8);
    qf[qt][1] = ld_bf8(Qp + (qt * 16 + l16) * DH + 32 + quad * 8);
  }

  f32x4 Ot[4][2] = {};           // [d-tile][q-tile], O^T C-layout
  float lrun[2] = {0.0f, 0.0f};  // per-lane partial sums (q = l16)

  // ---- staging constants (global side carries the swizzle) ----
  int lrow = lane >> 3;            // 0..7 (row within 8-row DMA chunk)
  int lcb = (lane & 7) ^ lrow;     // swizzled global col-block
  const u16* kdma[2];
  const u16* vdma[2];
  u16* kl[2];
  u16* vl[2];
#pragma unroll
  for (int i = 0; i < 2; ++i) {
    int chunk = wave * 2 + i;      // 0..7, 8 rows each
    kdma[i] = Kp + (size_t)(chunk * 8 + lrow) * DH + lcb * 8;
    vdma[i] = Vp + (size_t)(chunk * 8 + lrow) * SS + lcb * 8;
    kl[i] = &Ks[0][chunk * 8][0];
    vl[i] = &Vts[0][chunk * 8][0];
  }

  // ---- hoisted frag pointers (loop addressing = base + literal) ----
  int e7 = l16 & 7, qh = quad >> 1, qp = quad & 1;
  const u16* kfr0 = &Ks[0][l16][(quad ^ e7) * 8];        // d-blocks 0..3
  const u16* kfr1 = &Ks[0][l16][((quad + 4) ^ e7) * 8];  // d-blocks 4..7
  const u16* vfr[4];
#pragma unroll
  for (int c = 0; c < 4; ++c)
    vfr[c] = &Vts[0][l16][((2 * c + qh) ^ e7) * 8 + qp * 4];

  // ---- prestage tile kv=0 into buffer 0 ----
#pragma unroll
  for (int i = 0; i < 2; ++i) {
    __builtin_amdgcn_global_load_lds(
        (const __attribute__((address_space(1))) void*)kdma[i],
        (__attribute__((address_space(3))) void*)kl[i], 16, 0, 0);
    __builtin_amdgcn_global_load_lds(
        (const __attribute__((address_space(1))) void*)vdma[i],
        (__attribute__((address_space(3))) void*)vl[i], 16, 0, 0);
  }
  __syncthreads();

  int kv = 64;  // next tile to stage

#define ATTN_STEP(P)                                                          \
  {                                                                           \
    f32x4 s[2][4];                                                            \
    _Pragma("unroll") for (int t = 0; t < 4; ++t) {                           \
      bf16x8 kb0 = *(const bf16x8*)(kfr0 + (P) * 4096 + t * 1024);            \
      bf16x8 kb1 = *(const bf16x8*)(kfr1 + (P) * 4096 + t * 1024);            \
      _Pragma("unroll") for (int qt = 0; qt < 2; ++qt) {                      \
        f32x4 z = {};                                                         \
        z = MFMA16(kb0, qf[qt][0], z);                                        \
        z = MFMA16(kb1, qf[qt][1], z);                                        \
        s[qt][t] = z;                                                         \
      }                                                                       \
    }                                                                         \
    if (kv < SS) {                                                            \
      _Pragma("unroll") for (int i = 0; i < 2; ++i) {                         \
        __builtin_amdgcn_global_load_lds(                                     \
            (const __attribute__((address_space(1))) void*)(kdma[i] +         \
                                                            (size_t)kv * DH), \
            (__attribute__((address_space(3))) void*)(kl[i] +                 \
                                                      (1 - (P)) * 4096),      \
            16, 0, 0);                                                        \
        __builtin_amdgcn_global_load_lds(                                     \
            (const __attribute__((address_space(1))) void*)(vdma[i] + kv),    \
            (__attribute__((address_space(3))) void*)(vl[i] +                 \
                                                      (1 - (P)) * 4096),      \
            16, 0, 0);                                                        \
      }                                                                       \
    }                                                                         \
    bf16x4 pb[2][4];                                                          \
    _Pragma("unroll") for (int qt = 0; qt < 2; ++qt)                          \
        _Pragma("unroll") for (int t = 0; t < 4; ++t) {                       \
      unsigned u0 = __builtin_bit_cast(                                       \
          unsigned, __builtin_amdgcn_exp2f(s[qt][t][0]));                     \
      unsigned u1 = __builtin_bit_cast(                                       \
          unsigned, __builtin_amdgcn_exp2f(s[qt][t][1]));                     \
      unsigned u2 = __builtin_bit_cast(                                       \
          unsigned, __builtin_amdgcn_exp2f(s[qt][t][2]));                     \
      unsigned u3 = __builtin_bit_cast(                                       \
          unsigned, __builtin_amdgcn_exp2f(s[qt][t][3]));                     \
      unsigned w0 = __builtin_amdgcn_perm(u1, u0, 0x07060302u);               \
      unsigned w1 = __builtin_amdgcn_perm(u3, u2, 0x07060302u);               \
      lrun[qt] += __builtin_bit_cast(float, w0 << 16) +                       \
                  __builtin_bit_cast(float, w0 & 0xffff0000u) +               \
                  __builtin_bit_cast(float, w1 << 16) +                       \
                  __builtin_bit_cast(float, w1 & 0xffff0000u);                \
      uintx2 w;                                                               \
      w[0] = w0;                                                              \
      w[1] = w1;                                                              \
      pb[qt][t] = __builtin_bit_cast(bf16x4, w);                              \
    }                                                                         \
    _Pragma("unroll") for (int c = 0; c < 4; ++c)                             \
        _Pragma("unroll") for (int dt = 0; dt < 4; ++dt) {                    \
      bf16x4 va = *(const bf16x4*)(vfr[c] + (P) * 4096 + dt * 1024);          \
      _Pragma("unroll") for (int qt = 0; qt < 2; ++qt)                        \
          Ot[dt][qt] = MFMA16K16(va, pb[qt][c], Ot[dt][qt]);                  \
    }                                                                         \
    __syncthreads();                                                          \
    kv += 64;                                                                 \
  }

  for (int it = 0; it < SS / 128; ++it) {
    ATTN_STEP(0);
    ATTN_STEP(1);
  }
#undef ATTN_STEP

  // final normalizer: lanes {l16, +16, +32, +48} hold q=l16 partials
  float inv[2];
#pragma unroll
  for (int qt = 0; qt < 2; ++qt) {
    float l = lrun[qt];
    l += __shfl_xor(l, 16);
    l += __shfl_xor(l, 32);
    inv[qt] = 1.0f / l;
  }

  // write O^T: per lane q = l16 (fixed), d = dt*16 + quad*4 + r (contiguous)
#pragma unroll
  for (int qt = 0; qt < 2; ++qt) {
    int q = q0 + wave * 32 + qt * 16 + l16;
    size_t ob = ((size_t)b * SS + q) * DM + h * DH;
#pragma unroll
    for (int dt = 0; dt < 4; ++dt) {
      uintx2 o;
      o[0] = pack2bf(Ot[dt][qt][0] * inv[qt], Ot[dt][qt][1] * inv[qt]);
      o[1] = pack2bf(Ot[dt][qt][2] * inv[qt], Ot[dt][qt][3] * inv[qt]);
      *(uintx2*)(&ctx[ob + dt * 16 + quad * 4]) = o;
    }
  }
}

extern "C" void kernel_launch(void* const* d_in, const int* in_sizes, int n_in,
                              void* d_out, int out_size, void* d_ws, size_t ws_size,
                              hipStream_t stream) {
  const float* x  = (const float*)d_in[0];
  const float* Wq = (const float*)d_in[1];
  const float* bq = (const float*)d_in[2];
  const float* Wk = (const float*)d_in[3];
  const float* bk = (const float*)d_in[4];
  const float* Wv = (const float*)d_in[5];
  const float* bv = (const float*)d_in[6];
  const float* Wo = (const float*)d_in[7];
  const float* bo = (const float*)d_in[8];
  float* out = (float*)d_out;

  char* ws = (char*)d_ws;
  u16* xb = (u16*)(ws);                        // 16 MB  [8192,1024] bf16
  u16* Wt = (u16*)(ws + (16u << 20));          //  8 MB  [4096,1024] bf16
  u16* Qb = (u16*)(ws + (24u << 20));          // 16 MB  [B,H,S,Dh] (pre-scaled)
  u16* Kb = (u16*)(ws + (40u << 20));          // 16 MB  [B,H,S,Dh]
  u16* VT = (u16*)(ws + (56u << 20));          // 16 MB  [B,H,Dh,S]
  u16* Cb = (u16*)(ws + (72u << 20));          // 16 MB  [B,S,D] bf16 ctx

  k_prep<<<8192 + 4096, 256, 0, stream>>>(x, xb, Wq, Wk, Wv, Wo, Wt);
  k_gemm3<<<dim3(64, 12), 512, 0, stream>>>(
      xb, Wt, bq, bk, bv, Qb, Kb, VT);
  k_attn<<<dim3(SS / 128, NH, BB), 256, 0, stream>>>(Qb, Kb, VT, Cb);
  k_gemm<<<dim3(MROWS / 128, 8), 256, 0, stream>>>(
      Cb, Wt + (size_t)3 * DM * DM, MROWS, DM, DM, bo, out);
}

// Round 11
// 291.118 us; speedup vs baseline: 1.0511x; 1.0024x over previous
//
#include <hip/hip_runtime.h>
#include <hip/hip_bf16.h>

#define DM 1024
#define NH 16
#define DH 64
#define BB 4
#define SS 2048
#define MROWS (BB*SS)   // 8192

typedef unsigned short u16;
typedef short bf16x8 __attribute__((ext_vector_type(8)));
typedef short bf16x4 __attribute__((ext_vector_type(4)));
typedef float f32x4 __attribute__((ext_vector_type(4)));
typedef unsigned uintx2 __attribute__((ext_vector_type(2)));
typedef unsigned uintx4 __attribute__((ext_vector_type(4)));

#define MFMA16(a, b, c) __builtin_amdgcn_mfma_f32_16x16x32_bf16((a), (b), (c), 0, 0, 0)
#define MFMA16K16(a, b, c) __builtin_amdgcn_mfma_f32_16x16x16bf16_1k((a), (b), (c), 0, 0, 0)

__device__ __forceinline__ u16 f2bf(float f) {
  union { float f; unsigned u; } v; v.f = f;
  unsigned u = v.u;
  return (u16)((u + 0x7fffu + ((u >> 16) & 1u)) >> 16);
}

// pack two floats -> u32 of two RNE bf16 (lo = a, hi = b)
__device__ __forceinline__ unsigned pack2bf(float a, float b) {
  __hip_bfloat162 h = __float22bfloat162_rn(make_float2(a, b));
  unsigned u;
  __builtin_memcpy(&u, &h, 4);
  return u;
}

__device__ __forceinline__ bf16x8 ld_bf8(const u16* p) {
  return *(const bf16x8*)p;
}

// -------- merged prep: x cvt (blocks 0..8191) + W transpose (8192..9215) --
// tw (R17): 64x64 tile/block, float4 reads (256B contiguous segments vs the
// old 128B), LDS [64][69] f32 (69%32=5, gcd(5,32)=1 -> conflict-free column
// reads), 32B transposed writes. Same mapping Wt[n][k] = bf16(W[k][n]).
__global__ __launch_bounds__(256) void k_prep(const float* __restrict__ x,
                                              u16* __restrict__ xb,
                                              const float* __restrict__ Wq,
                                              const float* __restrict__ Wk,
                                              const float* __restrict__ Wv,
                                              const float* __restrict__ Wo,
                                              u16* __restrict__ Wt) {
  int bid = blockIdx.x, tid = threadIdx.x;
  if (bid < 8192) {
    int i = (bid * 256 + tid) * 4;
    float4 v = *(const float4*)(x + i);
    ushort4 o;
    o.x = f2bf(v.x); o.y = f2bf(v.y); o.z = f2bf(v.z); o.w = f2bf(v.w);
    *(ushort4*)(xb + i) = o;
    return;
  }
  __shared__ float ts[64][69];
  int b2 = bid - 8192;            // 0..1023
  int seg = b2 >> 8;              // 0..3
  int t2 = b2 & 255;
  int k0 = (t2 & 15) * 64;
  int n0 = (t2 >> 4) * 64;
  const float* W = seg == 0 ? Wq : seg == 1 ? Wk : seg == 2 ? Wv : Wo;
#pragma unroll
  for (int p = 0; p < 4; ++p) {
    int kr = p * 16 + (tid >> 4);      // 0..63
    int nc = (tid & 15) * 4;
    float4 v = *(const float4*)(&W[(size_t)(k0 + kr) * DM + n0 + nc]);
    ts[kr][nc] = v.x; ts[kr][nc + 1] = v.y;
    ts[kr][nc + 2] = v.z; ts[kr][nc + 3] = v.w;
  }
  __syncthreads();
  int r = tid >> 2;                    // 0..63 (n within tile)
  int c0 = (tid & 3) * 16;             // k offset
  u16 tmp[16];
#pragma unroll
  for (int j = 0; j < 16; ++j) tmp[j] = f2bf(ts[c0 + j][r]);
  u16* dst = &Wt[(size_t)(seg * DM + n0 + r) * DM + k0 + c0];
  *(uintx4*)(dst) = *(const uintx4*)(&tmp[0]);
  *(uintx4*)(dst + 8) = *(const uintx4*)(&tmp[8]);
}

// ------- QKV GEMM: 128x256 tile, BK=64, TRIPLE-buffered, 768 wgs ---------
// (R16 structure, unchanged from R10's best)
__global__ __launch_bounds__(512, 1) void k_gemm3(
    const u16* __restrict__ A, const u16* __restrict__ Bt,
    const float* __restrict__ b0, const float* __restrict__ b1,
    const float* __restrict__ b2,
    u16* __restrict__ oq, u16* __restrict__ ok, u16* __restrict__ ov) {
  __shared__ __align__(16) u16 As[3][128][64];  // 48 KB
  __shared__ __align__(16) u16 Bs[3][256][64];  // 96 KB
  const int K = DM;
  int tid = threadIdx.x;
  int wave = tid >> 6, lane = tid & 63, quad = lane >> 4, l16 = lane & 15;
  int wr = wave >> 2, wc = wave & 3;
  int g = blockIdx.x + 64 * blockIdx.y;
  int xcd = g & 7, idx = g >> 3;           // idx 0..95
  int bm = (xcd * 8 + (idx & 7)) * 128;
  int bn = (idx >> 3) * 256;

  f32x4 acc[4][4] = {};

  int srow = wave * 8 + (lane >> 3);
  int scol = ((lane & 7) ^ (lane >> 3)) * 8;
  const u16* ga = A + (size_t)(bm + srow) * K + scol;
  const u16* gb = Bt + (size_t)(bn + srow) * K + scol;
  u16* aw0 = &As[0][wave * 8][0];
  u16* aw1 = &As[1][wave * 8][0];
  u16* aw2 = &As[2][wave * 8][0];
  u16* bw0 = &Bs[0][wave * 8][0];
  u16* bw1 = &Bs[1][wave * 8][0];
  u16* bw2 = &Bs[2][wave * 8][0];

  int e7 = l16 & 7;
  int blk0 = ((quad) ^ e7) * 8, blk1 = ((4 + quad) ^ e7) * 8;
  const u16* aP0_0 = &As[0][wr * 64 + l16][0] + blk0;
  const u16* aP0_1 = &As[0][wr * 64 + l16][0] + blk1;
  const u16* aP1_0 = &As[1][wr * 64 + l16][0] + blk0;
  const u16* aP1_1 = &As[1][wr * 64 + l16][0] + blk1;
  const u16* aP2_0 = &As[2][wr * 64 + l16][0] + blk0;
  const u16* aP2_1 = &As[2][wr * 64 + l16][0] + blk1;
  const u16* bP0_0 = &Bs[0][wc * 64 + l16][0] + blk0;
  const u16* bP0_1 = &Bs[0][wc * 64 + l16][0] + blk1;
  const u16* bP1_0 = &Bs[1][wc * 64 + l16][0] + blk0;
  const u16* bP1_1 = &Bs[1][wc * 64 + l16][0] + blk1;
  const u16* bP2_0 = &Bs[2][wc * 64 + l16][0] + blk0;
  const u16* bP2_1 = &Bs[2][wc * 64 + l16][0] + blk1;

#define SBAR()                            \
  {                                       \
    asm volatile("" ::: "memory");        \
    __builtin_amdgcn_s_barrier();         \
    asm volatile("" ::: "memory");        \
  }

#define GLD(gp, lp)                                                \
  __builtin_amdgcn_global_load_lds(                                \
      (const __attribute__((address_space(1))) void*)(gp),         \
      (__attribute__((address_space(3))) void*)(lp), 16, 0, 0)

#define STG_ALL(KT, SB)                                            \
  {                                                                \
    size_t ko = (size_t)(KT) * 64;                                 \
    GLD(gb + ko, bw##SB);                                          \
    GLD(gb + (size_t)64 * K + ko, bw##SB + 4096);                  \
    GLD(gb + (size_t)128 * K + ko, bw##SB + 8192);                 \
    GLD(gb + (size_t)192 * K + ko, bw##SB + 12288);                \
    GLD(ga + ko, aw##SB);                                          \
    GLD(ga + (size_t)64 * K + ko, aw##SB + 4096);                  \
  }

#define MM2(M0, M1)                                                \
  _Pragma("unroll") for (int n = 0; n < 4; ++n) {                  \
    acc[M0][n] = MFMA16(afA0, bfr[n][0], acc[M0][n]);              \
    acc[M0][n] = MFMA16(afA1, bfr[n][1], acc[M0][n]);              \
    acc[M1][n] = MFMA16(afB0, bfr[n][0], acc[M1][n]);              \
    acc[M1][n] = MFMA16(afB1, bfr[n][1], acc[M1][n]);              \
  }

#define VM6() asm volatile("s_waitcnt vmcnt(6)" ::: "memory")
#define VM0() asm volatile("s_waitcnt vmcnt(0)" ::: "memory")
#define VMNONE()

#define TILE(T, BUF, SB, DOSTAGE, WAITOP)                                     \
  {                                                                           \
    bf16x8 bfr[4][2];                                                         \
    _Pragma("unroll") for (int n = 0; n < 4; ++n) {                           \
      bfr[n][0] = *(const bf16x8*)(bP##BUF##_0 + n * 1024);                   \
      bfr[n][1] = *(const bf16x8*)(bP##BUF##_1 + n * 1024);                   \
    }                                                                         \
    bf16x8 afA0 = *(const bf16x8*)(aP##BUF##_0 + 0 * 1024);                   \
    bf16x8 afA1 = *(const bf16x8*)(aP##BUF##_1 + 0 * 1024);                   \
    bf16x8 afB0 = *(const bf16x8*)(aP##BUF##_0 + 1 * 1024);                   \
    bf16x8 afB1 = *(const bf16x8*)(aP##BUF##_1 + 1 * 1024);                   \
    if (DOSTAGE) STG_ALL((T) + 2, SB);                                        \
    SBAR();                                                                   \
    __builtin_amdgcn_s_setprio(1);                                            \
    MM2(0, 1);                                                                \
    __builtin_amdgcn_s_setprio(0);                                            \
    SBAR();                                                                   \
    afA0 = *(const bf16x8*)(aP##BUF##_0 + 2 * 1024);                          \
    afA1 = *(const bf16x8*)(aP##BUF##_1 + 2 * 1024);                          \
    afB0 = *(const bf16x8*)(aP##BUF##_0 + 3 * 1024);                          \
    afB1 = *(const bf16x8*)(aP##BUF##_1 + 3 * 1024);                          \
    SBAR();                                                                   \
    __builtin_amdgcn_s_setprio(1);                                            \
    MM2(2, 3);                                                                \
    __builtin_amdgcn_s_setprio(0);                                            \
    WAITOP();                                                                 \
    SBAR();                                                                   \
  }

  STG_ALL(0, 0);
  STG_ALL(1, 1);
  VM6();
  SBAR();

#pragma unroll 1
  for (int t3 = 0; t3 < 4; ++t3) {   // tiles 0..11
    int t = t3 * 3;
    TILE(t, 0, 2, 1, VM6);
    TILE(t + 1, 1, 0, 1, VM6);
    TILE(t + 2, 2, 1, 1, VM6);
  }
  TILE(12, 0, 2, 1, VM6);
  TILE(13, 1, 0, 1, VM6);
  TILE(14, 2, 1, 0, VM0);
  TILE(15, 0, 1, 0, VMNONE);

#undef TILE
#undef VMNONE
#undef VM0
#undef VM6
#undef MM2
#undef STG_ALL
#undef GLD
#undef SBAR

  int seg = bn >> 10;
  const float* bia = seg == 0 ? b0 : seg == 1 ? b1 : b2;
  int cb = bn & 1023;
  if (seg == 2) {
#pragma unroll
    for (int m = 0; m < 4; ++m)
#pragma unroll
      for (int n = 0; n < 4; ++n) {
        int row = bm + wr * 64 + m * 16 + quad * 4;
        int col = cb + wc * 64 + n * 16 + l16;
        float bv_ = bia[col];
        int bb2 = row >> 11, s = row & 2047, hh = col >> 6, dh = col & 63;
        ushort4 o4;
        o4.x = f2bf(acc[m][n][0] + bv_);
        o4.y = f2bf(acc[m][n][1] + bv_);
        o4.z = f2bf(acc[m][n][2] + bv_);
        o4.w = f2bf(acc[m][n][3] + bv_);
        *(ushort4*)(&ov[(((size_t)bb2 * NH + hh) * DH + dh) * SS + s]) = o4;
      }
  } else {
    u16* o = seg == 0 ? oq : ok;
    float sc = seg == 0 ? (0.125f * 1.44269504f) : 1.0f;
#pragma unroll
    for (int m = 0; m < 4; ++m)
#pragma unroll
      for (int n = 0; n < 4; ++n)
#pragma unroll
        for (int r = 0; r < 4; ++r) {
          int row = bm + wr * 64 + m * 16 + quad * 4 + r;
          int col = cb + wc * 64 + n * 16 + l16;
          float v = (acc[m][n][r] + bia[col]) * sc;
          int bb2 = row >> 11, s = row & 2047, hh = col >> 6, dh = col & 63;
          o[((((size_t)bb2 * NH + hh) * SS) + s) * DH + dh] = f2bf(v);
        }
  }
}

// ------- out-proj GEMM: 128x256, BK=64, triple-buffered, 256 wgs ---------
// R17: same structure as k_gemm3 (proven); grid (64,4) = 256 wgs = exactly
// ONE round on 256 CUs (old 128^2 kernel was 512 wgs = 2 rounds + BK=32
// 2-phase). f32 epilogue with bias. Same K order -> bitwise-equal output.
__global__ __launch_bounds__(512, 1) void k_gemmo(
    const u16* __restrict__ A, const u16* __restrict__ Bt,
    const float* __restrict__ b0, float* __restrict__ of) {
  __shared__ __align__(16) u16 As[3][128][64];  // 48 KB
  __shared__ __align__(16) u16 Bs[3][256][64];  // 96 KB
  const int K = DM;
  int tid = threadIdx.x;
  int wave = tid >> 6, lane = tid & 63, quad = lane >> 4, l16 = lane & 15;
  int wr = wave >> 2, wc = wave & 3;
  // bijective XCD map over 256 wgs: xcd owns 8 bm x 4 bn
  int g = blockIdx.x + 64 * blockIdx.y;
  int xcd = g & 7, idx = g >> 3;           // idx 0..31
  int bm = (xcd * 8 + (idx & 7)) * 128;
  int bn = (idx >> 3) * 256;

  f32x4 acc[4][4] = {};

  int srow = wave * 8 + (lane >> 3);
  int scol = ((lane & 7) ^ (lane >> 3)) * 8;
  const u16* ga = A + (size_t)(bm + srow) * K + scol;
  const u16* gb = Bt + (size_t)(bn + srow) * K + scol;
  u16* aw0 = &As[0][wave * 8][0];
  u16* aw1 = &As[1][wave * 8][0];
  u16* aw2 = &As[2][wave * 8][0];
  u16* bw0 = &Bs[0][wave * 8][0];
  u16* bw1 = &Bs[1][wave * 8][0];
  u16* bw2 = &Bs[2][wave * 8][0];

  int e7 = l16 & 7;
  int blk0 = ((quad) ^ e7) * 8, blk1 = ((4 + quad) ^ e7) * 8;
  const u16* aP0_0 = &As[0][wr * 64 + l16][0] + blk0;
  const u16* aP0_1 = &As[0][wr * 64 + l16][0] + blk1;
  const u16* aP1_0 = &As[1][wr * 64 + l16][0] + blk0;
  const u16* aP1_1 = &As[1][wr * 64 + l16][0] + blk1;
  const u16* aP2_0 = &As[2][wr * 64 + l16][0] + blk0;
  const u16* aP2_1 = &As[2][wr * 64 + l16][0] + blk1;
  const u16* bP0_0 = &Bs[0][wc * 64 + l16][0] + blk0;
  const u16* bP0_1 = &Bs[0][wc * 64 + l16][0] + blk1;
  const u16* bP1_0 = &Bs[1][wc * 64 + l16][0] + blk0;
  const u16* bP1_1 = &Bs[1][wc * 64 + l16][0] + blk1;
  const u16* bP2_0 = &Bs[2][wc * 64 + l16][0] + blk0;
  const u16* bP2_1 = &Bs[2][wc * 64 + l16][0] + blk1;

#define SBAR()                            \
  {                                       \
    asm volatile("" ::: "memory");        \
    __builtin_amdgcn_s_barrier();         \
    asm volatile("" ::: "memory");        \
  }

#define GLD(gp, lp)                                                \
  __builtin_amdgcn_global_load_lds(                                \
      (const __attribute__((address_space(1))) void*)(gp),         \
      (__attribute__((address_space(3))) void*)(lp), 16, 0, 0)

#define STG_ALL(KT, SB)                                            \
  {                                                                \
    size_t ko = (size_t)(KT) * 64;                                 \
    GLD(gb + ko, bw##SB);                                          \
    GLD(gb + (size_t)64 * K + ko, bw##SB + 4096);                  \
    GLD(gb + (size_t)128 * K + ko, bw##SB + 8192);                 \
    GLD(gb + (size_t)192 * K + ko, bw##SB + 12288);                \
    GLD(ga + ko, aw##SB);                                          \
    GLD(ga + (size_t)64 * K + ko, aw##SB + 4096);                  \
  }

#define MM2(M0, M1)                                                \
  _Pragma("unroll") for (int n = 0; n < 4; ++n) {                  \
    acc[M0][n] = MFMA16(afA0, bfr[n][0], acc[M0][n]);              \
    acc[M0][n] = MFMA16(afA1, bfr[n][1], acc[M0][n]);              \
    acc[M1][n] = MFMA16(afB0, bfr[n][0], acc[M1][n]);              \
    acc[M1][n] = MFMA16(afB1, bfr[n][1], acc[M1][n]);              \
  }

#define VM6() asm volatile("s_waitcnt vmcnt(6)" ::: "memory")
#define VM0() asm volatile("s_waitcnt vmcnt(0)" ::: "memory")
#define VMNONE()

#define TILE(T, BUF, SB, DOSTAGE, WAITOP)                                     \
  {                                                                           \
    bf16x8 bfr[4][2];                                                         \
    _Pragma("unroll") for (int n = 0; n < 4; ++n) {                           \
      bfr[n][0] = *(const bf16x8*)(bP##BUF##_0 + n * 1024);                   \
      bfr[n][1] = *(const bf16x8*)(bP##BUF##_1 + n * 1024);                   \
    }                                                                         \
    bf16x8 afA0 = *(const bf16x8*)(aP##BUF##_0 + 0 * 1024);                   \
    bf16x8 afA1 = *(const bf16x8*)(aP##BUF##_1 + 0 * 1024);                   \
    bf16x8 afB0 = *(const bf16x8*)(aP##BUF##_0 + 1 * 1024);                   \
    bf16x8 afB1 = *(const bf16x8*)(aP##BUF##_1 + 1 * 1024);                   \
    if (DOSTAGE) STG_ALL((T) + 2, SB);                                        \
    SBAR();                                                                   \
    __builtin_amdgcn_s_setprio(1);                                            \
    MM2(0, 1);                                                                \
    __builtin_amdgcn_s_setprio(0);                                            \
    SBAR();                                                                   \
    afA0 = *(const bf16x8*)(aP##BUF##_0 + 2 * 1024);                          \
    afA1 = *(const bf16x8*)(aP##BUF##_1 + 2 * 1024);                          \
    afB0 = *(const bf16x8*)(aP##BUF##_0 + 3 * 1024);                          \
    afB1 = *(const bf16x8*)(aP##BUF##_1 + 3 * 1024);                          \
    SBAR();                                                                   \
    __builtin_amdgcn_s_setprio(1);                                            \
    MM2(2, 3);                                                                \
    __builtin_amdgcn_s_setprio(0);                                            \
    WAITOP();                                                                 \
    SBAR();                                                                   \
  }

  STG_ALL(0, 0);
  STG_ALL(1, 1);
  VM6();
  SBAR();

#pragma unroll 1
  for (int t3 = 0; t3 < 4; ++t3) {   // tiles 0..11
    int t = t3 * 3;
    TILE(t, 0, 2, 1, VM6);
    TILE(t + 1, 1, 0, 1, VM6);
    TILE(t + 2, 2, 1, 1, VM6);
  }
  TILE(12, 0, 2, 1, VM6);
  TILE(13, 1, 0, 1, VM6);
  TILE(14, 2, 1, 0, VM0);
  TILE(15, 0, 1, 0, VMNONE);

#undef TILE
#undef VMNONE
#undef VM0
#undef VM6
#undef MM2
#undef STG_ALL
#undef GLD
#undef SBAR

  // ---- epilogue: f32 out + bias ----
#pragma unroll
  for (int m = 0; m < 4; ++m)
#pragma unroll
    for (int n = 0; n < 4; ++n)
#pragma unroll
      for (int r = 0; r < 4; ++r) {
        int row = bm + wr * 64 + m * 16 + quad * 4 + r;
        int col = bn + wc * 64 + n * 16 + l16;
        of[(size_t)row * DM + col] = acc[m][n][r] + b0[col];
      }
}

// ---------------- flash attention (R0-exact single dispatch) --------------
__global__ __launch_bounds__(256) void k_attn(const u16* __restrict__ Q,
                                              const u16* __restrict__ Kg,
                                              const u16* __restrict__ VT,
                                              u16* __restrict__ ctx) {
  __shared__ __align__(16) u16 Ks[2][64][64];
  __shared__ __align__(16) u16 Vts[2][64][64];  // [d][kv], swizzled
  int tid = threadIdx.x;
  int wave = tid >> 6, lane = tid & 63, quad = lane >> 4, l16 = lane & 15;
  int q0 = blockIdx.x * 128;
  int h = blockIdx.y, b = blockIdx.z;
  size_t bh = ((size_t)b * NH + h) * SS * DH;
  const u16* Qp = Q + bh + (size_t)(q0 + wave * 32) * DH;
  const u16* Kp = Kg + bh;
  const u16* Vp = VT + ((size_t)b * NH + h) * DH * SS;  // [Dh][S]

  bf16x8 qf[2][2];
#pragma unroll
  for (int qt = 0; qt < 2; ++qt) {
    qf[qt][0] = ld_bf8(Qp + (qt * 16 + l16) * DH + quad * 8);
    qf[qt][1] = ld_bf8(Qp + (qt * 16 + l16) * DH + 32 + quad * 8);
  }

  f32x4 Ot[4][2] = {};           // [d-tile][q-tile], O^T C-layout
  float lrun[2] = {0.0f, 0.0f};  // per-lane partial sums (q = l16)

  int lrow = lane >> 3;            // 0..7 (row within 8-row DMA chunk)
  int lcb = (lane & 7) ^ lrow;     // swizzled global col-block
  const u16* kdma[2];
  const u16* vdma[2];
  u16* kl[2];
  u16* vl[2];
#pragma unroll
  for (int i = 0; i < 2; ++i) {
    int chunk = wave * 2 + i;      // 0..7, 8 rows each
    kdma[i] = Kp + (size_t)(chunk * 8 + lrow) * DH + lcb * 8;
    vdma[i] = Vp + (size_t)(chunk * 8 + lrow) * SS + lcb * 8;
    kl[i] = &Ks[0][chunk * 8][0];
    vl[i] = &Vts[0][chunk * 8][0];
  }

  int e7 = l16 & 7, qh = quad >> 1, qp = quad & 1;
  const u16* kfr0 = &Ks[0][l16][(quad ^ e7) * 8];        // d-blocks 0..3
  const u16* kfr1 = &Ks[0][l16][((quad + 4) ^ e7) * 8];  // d-blocks 4..7
  const u16* vfr[4];
#pragma unroll
  for (int c = 0; c < 4; ++c)
    vfr[c] = &Vts[0][l16][((2 * c + qh) ^ e7) * 8 + qp * 4];

#pragma unroll
  for (int i = 0; i < 2; ++i) {
    __builtin_amdgcn_global_load_lds(
        (const __attribute__((address_space(1))) void*)kdma[i],
        (__attribute__((address_space(3))) void*)kl[i], 16, 0, 0);
    __builtin_amdgcn_global_load_lds(
        (const __attribute__((address_space(1))) void*)vdma[i],
        (__attribute__((address_space(3))) void*)vl[i], 16, 0, 0);
  }
  __syncthreads();

  int kv = 64;  // next tile to stage

#define ATTN_STEP(P)                                                          \
  {                                                                           \
    f32x4 s[2][4];                                                            \
    _Pragma("unroll") for (int t = 0; t < 4; ++t) {                           \
      bf16x8 kb0 = *(const bf16x8*)(kfr0 + (P) * 4096 + t * 1024);            \
      bf16x8 kb1 = *(const bf16x8*)(kfr1 + (P) * 4096 + t * 1024);            \
      _Pragma("unroll") for (int qt = 0; qt < 2; ++qt) {                      \
        f32x4 z = {};                                                         \
        z = MFMA16(kb0, qf[qt][0], z);                                        \
        z = MFMA16(kb1, qf[qt][1], z);                                        \
        s[qt][t] = z;                                                         \
      }                                                                       \
    }                                                                         \
    if (kv < SS) {                                                            \
      _Pragma("unroll") for (int i = 0; i < 2; ++i) {                         \
        __builtin_amdgcn_global_load_lds(                                     \
            (const __attribute__((address_space(1))) void*)(kdma[i] +         \
                                                            (size_t)kv * DH), \
            (__attribute__((address_space(3))) void*)(kl[i] +                 \
                                                      (1 - (P)) * 4096),      \
            16, 0, 0);                                                        \
        __builtin_amdgcn_global_load_lds(                                     \
            (const __attribute__((address_space(1))) void*)(vdma[i] + kv),    \
            (__attribute__((address_space(3))) void*)(vl[i] +                 \
                                                      (1 - (P)) * 4096),      \
            16, 0, 0);                                                        \
      }                                                                       \
    }                                                                         \
    bf16x4 pb[2][4];                                                          \
    _Pragma("unroll") for (int qt = 0; qt < 2; ++qt)                          \
        _Pragma("unroll") for (int t = 0; t < 4; ++t) {                       \
      unsigned u0 = __builtin_bit_cast(                                       \
          unsigned, __builtin_amdgcn_exp2f(s[qt][t][0]));                     \
      unsigned u1 = __builtin_bit_cast(                                       \
          unsigned, __builtin_amdgcn_exp2f(s[qt][t][1]));                     \
      unsigned u2 = __builtin_bit_cast(                                       \
          unsigned, __builtin_amdgcn_exp2f(s[qt][t][2]));                     \
      unsigned u3 = __builtin_bit_cast(                                       \
          unsigned, __builtin_amdgcn_exp2f(s[qt][t][3]));                     \
      unsigned w0 = __builtin_amdgcn_perm(u1, u0, 0x07060302u);               \
      unsigned w1 = __builtin_amdgcn_perm(u3, u2, 0x07060302u);               \
      lrun[qt] += __builtin_bit_cast(float, w0 << 16) +                       \
                  __builtin_bit_cast(float, w0 & 0xffff0000u) +               \
                  __builtin_bit_cast(float, w1 << 16) +                       \
                  __builtin_bit_cast(float, w1 & 0xffff0000u);                \
      uintx2 w;                                                               \
      w[0] = w0;                                                              \
      w[1] = w1;                                                              \
      pb[qt][t] = __builtin_bit_cast(bf16x4, w);                              \
    }                                                                         \
    _Pragma("unroll") for (int c = 0; c < 4; ++c)                             \
        _Pragma("unroll") for (int dt = 0; dt < 4; ++dt) {                    \
      bf16x4 va = *(const bf16x4*)(vfr[c] + (P) * 4096 + dt * 1024);          \
      _Pragma("unroll") for (int qt = 0; qt < 2; ++qt)                        \
          Ot[dt][qt] = MFMA16K16(va, pb[qt][c], Ot[dt][qt]);                  \
    }                                                                         \
    __syncthreads();                                                          \
    kv += 64;                                                                 \
  }

  for (int it = 0; it < SS / 128; ++it) {
    ATTN_STEP(0);
    ATTN_STEP(1);
  }
#undef ATTN_STEP

  float inv[2];
#pragma unroll
  for (int qt = 0; qt < 2; ++qt) {
    float l = lrun[qt];
    l += __shfl_xor(l, 16);
    l += __shfl_xor(l, 32);
    inv[qt] = 1.0f / l;
  }

#pragma unroll
  for (int qt = 0; qt < 2; ++qt) {
    int q = q0 + wave * 32 + qt * 16 + l16;
    size_t ob = ((size_t)b * SS + q) * DM + h * DH;
#pragma unroll
    for (int dt = 0; dt < 4; ++dt) {
      uintx2 o;
      o[0] = pack2bf(Ot[dt][qt][0] * inv[qt], Ot[dt][qt][1] * inv[qt]);
      o[1] = pack2bf(Ot[dt][qt][2] * inv[qt], Ot[dt][qt][3] * inv[qt]);
      *(uintx2*)(&ctx[ob + dt * 16 + quad * 4]) = o;
    }
  }
}

extern "C" void kernel_launch(void* const* d_in, const int* in_sizes, int n_in,
                              void* d_out, int out_size, void* d_ws, size_t ws_size,
                              hipStream_t stream) {
  const float* x  = (const float*)d_in[0];
  const float* Wq = (const float*)d_in[1];
  const float* bq = (const float*)d_in[2];
  const float* Wk = (const float*)d_in[3];
  const float* bk = (const float*)d_in[4];
  const float* Wv = (const float*)d_in[5];
  const float* bv = (const float*)d_in[6];
  const float* Wo = (const float*)d_in[7];
  const float* bo = (const float*)d_in[8];
  float* out = (float*)d_out;

  char* ws = (char*)d_ws;
  u16* xb = (u16*)(ws);                        // 16 MB  [8192,1024] bf16
  u16* Wt = (u16*)(ws + (16u << 20));          //  8 MB  [4096,1024] bf16
  u16* Qb = (u16*)(ws + (24u << 20));          // 16 MB  [B,H,S,Dh] (pre-scaled)
  u16* Kb = (u16*)(ws + (40u << 20));          // 16 MB  [B,H,S,Dh]
  u16* VT = (u16*)(ws + (56u << 20));          // 16 MB  [B,H,Dh,S]
  u16* Cb = (u16*)(ws + (72u << 20));          // 16 MB  [B,S,D] bf16 ctx

  k_prep<<<8192 + 1024, 256, 0, stream>>>(x, xb, Wq, Wk, Wv, Wo, Wt);
  k_gemm3<<<dim3(64, 12), 512, 0, stream>>>(
      xb, Wt, bq, bk, bv, Qb, Kb, VT);
  k_attn<<<dim3(SS / 128, NH, BB), 256, 0, stream>>>(Qb, Kb, VT, Cb);
  k_gemmo<<<dim3(64, 4), 512, 0, stream>>>(
      Cb, Wt + (size_t)3 * DM * DM, bo, out);
}

// Round 13
// 276.309 us; speedup vs baseline: 1.1074x; 1.0536x over previous
//
#include <hip/hip_runtime.h>
#include <hip/hip_bf16.h>

#define DM 1024
#define NH 16
#define DH 64
#define BB 4
#define SS 2048
#define MROWS (BB*SS)   // 8192

typedef unsigned short u16;
typedef short bf16x8 __attribute__((ext_vector_type(8)));
typedef short bf16x4 __attribute__((ext_vector_type(4)));
typedef float f32x4 __attribute__((ext_vector_type(4)));
typedef unsigned uintx2 __attribute__((ext_vector_type(2)));
typedef unsigned uintx4 __attribute__((ext_vector_type(4)));

#define MFMA16(a, b, c) __builtin_amdgcn_mfma_f32_16x16x32_bf16((a), (b), (c), 0, 0, 0)
#define MFMA16K16(a, b, c) __builtin_amdgcn_mfma_f32_16x16x16bf16_1k((a), (b), (c), 0, 0, 0)

__device__ __forceinline__ u16 f2bf(float f) {
  union { float f; unsigned u; } v; v.f = f;
  unsigned u = v.u;
  return (u16)((u + 0x7fffu + ((u >> 16) & 1u)) >> 16);
}

__device__ __forceinline__ unsigned pack2bf(float a, float b) {
  __hip_bfloat162 h = __float22bfloat162_rn(make_float2(a, b));
  unsigned u;
  __builtin_memcpy(&u, &h, 4);
  return u;
}

__device__ __forceinline__ bf16x8 ld_bf8(const u16* p) {
  return *(const bf16x8*)p;
}

// -------- merged prep: x cvt (blocks 0..8191) + W transpose (8192..9215) --
__global__ __launch_bounds__(256) void k_prep(const float* __restrict__ x,
                                              u16* __restrict__ xb,
                                              const float* __restrict__ Wq,
                                              const float* __restrict__ Wk,
                                              const float* __restrict__ Wv,
                                              const float* __restrict__ Wo,
                                              u16* __restrict__ Wt) {
  int bid = blockIdx.x, tid = threadIdx.x;
  if (bid < 8192) {
    int i = (bid * 256 + tid) * 4;
    float4 v = *(const float4*)(x + i);
    ushort4 o;
    o.x = f2bf(v.x); o.y = f2bf(v.y); o.z = f2bf(v.z); o.w = f2bf(v.w);
    *(ushort4*)(xb + i) = o;
    return;
  }
  __shared__ float ts[64][69];
  int b2 = bid - 8192;            // 0..1023
  int seg = b2 >> 8;              // 0..3
  int t2 = b2 & 255;
  int k0 = (t2 & 15) * 64;
  int n0 = (t2 >> 4) * 64;
  const float* W = seg == 0 ? Wq : seg == 1 ? Wk : seg == 2 ? Wv : Wo;
#pragma unroll
  for (int p = 0; p < 4; ++p) {
    int kr = p * 16 + (tid >> 4);      // 0..63
    int nc = (tid & 15) * 4;
    float4 v = *(const float4*)(&W[(size_t)(k0 + kr) * DM + n0 + nc]);
    ts[kr][nc] = v.x; ts[kr][nc + 1] = v.y;
    ts[kr][nc + 2] = v.z; ts[kr][nc + 3] = v.w;
  }
  __syncthreads();
  int r = tid >> 2;                    // 0..63 (n within tile)
  int c0 = (tid & 3) * 16;             // k offset
  u16 tmp[16];
#pragma unroll
  for (int j = 0; j < 16; ++j) tmp[j] = f2bf(ts[c0 + j][r]);
  u16* dst = &Wt[(size_t)(seg * DM + n0 + r) * DM + k0 + c0];
  *(uintx4*)(dst) = *(const uintx4*)(&tmp[0]);
  *(uintx4*)(dst + 8) = *(const uintx4*)(&tmp[8]);
}

// ------- QKV GEMM: 128x256, BK=64, triple-buffered, ONE barrier/tile -----
// R18 vs R10/R11 (MfmaUtil 24%, 4 barriers/tile): mid-tile barriers served
// no data dependency (intra-tile deps are per-wave lgkm; cross-wave deps
// only at boundaries) and forced LDS-reads to serialize with MFMAs. New
// tile: {stage(t+2); read all 16 frags; 32 MFMA (compiler interleaves via
// lgkmcnt); vmcnt(6); SBAR}. Wait counts/positions = R10's proven scheme.
// Per-accumulator K order (s0 then s1) unchanged -> bitwise-identical.
__global__ __launch_bounds__(512, 1) void k_gemm3(
    const u16* __restrict__ A, const u16* __restrict__ Bt,
    const float* __restrict__ b0, const float* __restrict__ b1,
    const float* __restrict__ b2,
    u16* __restrict__ oq, u16* __restrict__ ok, u16* __restrict__ ov) {
  __shared__ __align__(16) u16 As[3][128][64];  // 48 KB
  __shared__ __align__(16) u16 Bs[3][256][64];  // 96 KB
  const int K = DM;
  int tid = threadIdx.x;
  int wave = tid >> 6, lane = tid & 63, quad = lane >> 4, l16 = lane & 15;
  int wr = wave >> 2, wc = wave & 3;
  int g = blockIdx.x + 64 * blockIdx.y;
  int xcd = g & 7, idx = g >> 3;           // idx 0..95
  int bm = (xcd * 8 + (idx & 7)) * 128;
  int bn = (idx >> 3) * 256;

  f32x4 acc[4][4] = {};

  int srow = wave * 8 + (lane >> 3);
  int scol = ((lane & 7) ^ (lane >> 3)) * 8;
  const u16* ga = A + (size_t)(bm + srow) * K + scol;
  const u16* gb = Bt + (size_t)(bn + srow) * K + scol;
  u16* aw0 = &As[0][wave * 8][0];
  u16* aw1 = &As[1][wave * 8][0];
  u16* aw2 = &As[2][wave * 8][0];
  u16* bw0 = &Bs[0][wave * 8][0];
  u16* bw1 = &Bs[1][wave * 8][0];
  u16* bw2 = &Bs[2][wave * 8][0];

  int e7 = l16 & 7;
  int blk0 = ((quad) ^ e7) * 8, blk1 = ((4 + quad) ^ e7) * 8;
  const u16* aP0_0 = &As[0][wr * 64 + l16][0] + blk0;
  const u16* aP0_1 = &As[0][wr * 64 + l16][0] + blk1;
  const u16* aP1_0 = &As[1][wr * 64 + l16][0] + blk0;
  const u16* aP1_1 = &As[1][wr * 64 + l16][0] + blk1;
  const u16* aP2_0 = &As[2][wr * 64 + l16][0] + blk0;
  const u16* aP2_1 = &As[2][wr * 64 + l16][0] + blk1;
  const u16* bP0_0 = &Bs[0][wc * 64 + l16][0] + blk0;
  const u16* bP0_1 = &Bs[0][wc * 64 + l16][0] + blk1;
  const u16* bP1_0 = &Bs[1][wc * 64 + l16][0] + blk0;
  const u16* bP1_1 = &Bs[1][wc * 64 + l16][0] + blk1;
  const u16* bP2_0 = &Bs[2][wc * 64 + l16][0] + blk0;
  const u16* bP2_1 = &Bs[2][wc * 64 + l16][0] + blk1;

#define SBAR()                            \
  {                                       \
    asm volatile("" ::: "memory");        \
    __builtin_amdgcn_s_barrier();         \
    asm volatile("" ::: "memory");        \
  }

#define GLD(gp, lp)                                                \
  __builtin_amdgcn_global_load_lds(                                \
      (const __attribute__((address_space(1))) void*)(gp),         \
      (__attribute__((address_space(3))) void*)(lp), 16, 0, 0)

#define STG_ALL(KT, SB)                                            \
  {                                                                \
    size_t ko = (size_t)(KT) * 64;                                 \
    GLD(gb + ko, bw##SB);                                          \
    GLD(gb + (size_t)64 * K + ko, bw##SB + 4096);                  \
    GLD(gb + (size_t)128 * K + ko, bw##SB + 8192);                 \
    GLD(gb + (size_t)192 * K + ko, bw##SB + 12288);                \
    GLD(ga + ko, aw##SB);                                          \
    GLD(ga + (size_t)64 * K + ko, aw##SB + 4096);                  \
  }

#define VM6() asm volatile("s_waitcnt vmcnt(6)" ::: "memory")
#define VM0() asm volatile("s_waitcnt vmcnt(0)" ::: "memory")
#define VMNONE()

#define TILE(T, BUF, SB, DOSTAGE, WAITOP)                                     \
  {                                                                           \
    if (DOSTAGE) STG_ALL((T) + 2, SB);                                        \
    bf16x8 bf0[4], bf1[4], af0[4], af1[4];                                    \
    _Pragma("unroll") for (int n = 0; n < 4; ++n) {                           \
      bf0[n] = *(const bf16x8*)(bP##BUF##_0 + n * 1024);                      \
      bf1[n] = *(const bf16x8*)(bP##BUF##_1 + n * 1024);                      \
    }                                                                         \
    _Pragma("unroll") for (int m = 0; m < 4; ++m) {                           \
      af0[m] = *(const bf16x8*)(aP##BUF##_0 + m * 1024);                      \
      af1[m] = *(const bf16x8*)(aP##BUF##_1 + m * 1024);                      \
    }                                                                         \
    __builtin_amdgcn_s_setprio(1);                                            \
    _Pragma("unroll") for (int m = 0; m < 4; ++m)                             \
        _Pragma("unroll") for (int n = 0; n < 4; ++n) {                       \
      acc[m][n] = MFMA16(af0[m], bf0[n], acc[m][n]);                          \
      acc[m][n] = MFMA16(af1[m], bf1[n], acc[m][n]);                          \
    }                                                                         \
    __builtin_amdgcn_s_setprio(0);                                            \
    WAITOP();                                                                 \
    SBAR();                                                                   \
  }

  STG_ALL(0, 0);
  STG_ALL(1, 1);
  VM6();
  SBAR();

#pragma unroll 1
  for (int t3 = 0; t3 < 4; ++t3) {   // tiles 0..11
    int t = t3 * 3;
    TILE(t, 0, 2, 1, VM6);
    TILE(t + 1, 1, 0, 1, VM6);
    TILE(t + 2, 2, 1, 1, VM6);
  }
  TILE(12, 0, 2, 1, VM6);
  TILE(13, 1, 0, 1, VM6);
  TILE(14, 2, 1, 0, VM0);
  TILE(15, 0, 1, 0, VMNONE);

#undef TILE
#undef VMNONE
#undef VM0
#undef VM6
#undef STG_ALL
#undef GLD
#undef SBAR

  int seg = bn >> 10;
  const float* bia = seg == 0 ? b0 : seg == 1 ? b1 : b2;
  int cb = bn & 1023;
  if (seg == 2) {
#pragma unroll
    for (int m = 0; m < 4; ++m)
#pragma unroll
      for (int n = 0; n < 4; ++n) {
        int row = bm + wr * 64 + m * 16 + quad * 4;
        int col = cb + wc * 64 + n * 16 + l16;
        float bv_ = bia[col];
        int bb2 = row >> 11, s = row & 2047, hh = col >> 6, dh = col & 63;
        ushort4 o4;
        o4.x = f2bf(acc[m][n][0] + bv_);
        o4.y = f2bf(acc[m][n][1] + bv_);
        o4.z = f2bf(acc[m][n][2] + bv_);
        o4.w = f2bf(acc[m][n][3] + bv_);
        *(ushort4*)(&ov[(((size_t)bb2 * NH + hh) * DH + dh) * SS + s]) = o4;
      }
  } else {
    u16* o = seg == 0 ? oq : ok;
    float sc = seg == 0 ? (0.125f * 1.44269504f) : 1.0f;
#pragma unroll
    for (int m = 0; m < 4; ++m)
#pragma unroll
      for (int n = 0; n < 4; ++n)
#pragma unroll
        for (int r = 0; r < 4; ++r) {
          int row = bm + wr * 64 + m * 16 + quad * 4 + r;
          int col = cb + wc * 64 + n * 16 + l16;
          float v = (acc[m][n][r] + bia[col]) * sc;
          int bb2 = row >> 11, s = row & 2047, hh = col >> 6, dh = col & 63;
          o[((((size_t)bb2 * NH + hh) * SS) + s) * DH + dh] = f2bf(v);
        }
  }
}

// ------- out-proj GEMM: same 1-barrier/tile structure, 256 wgs -----------
__global__ __launch_bounds__(512, 1) void k_gemmo(
    const u16* __restrict__ A, const u16* __restrict__ Bt,
    const float* __restrict__ b0, float* __restrict__ of) {
  __shared__ __align__(16) u16 As[3][128][64];  // 48 KB
  __shared__ __align__(16) u16 Bs[3][256][64];  // 96 KB
  const int K = DM;
  int tid = threadIdx.x;
  int wave = tid >> 6, lane = tid & 63, quad = lane >> 4, l16 = lane & 15;
  int wr = wave >> 2, wc = wave & 3;
  int g = blockIdx.x + 64 * blockIdx.y;
  int xcd = g & 7, idx = g >> 3;           // idx 0..31
  int bm = (xcd * 8 + (idx & 7)) * 128;
  int bn = (idx >> 3) * 256;

  f32x4 acc[4][4] = {};

  int srow = wave * 8 + (lane >> 3);
  int scol = ((lane & 7) ^ (lane >> 3)) * 8;
  const u16* ga = A + (size_t)(bm + srow) * K + scol;
  const u16* gb = Bt + (size_t)(bn + srow) * K + scol;
  u16* aw0 = &As[0][wave * 8][0];
  u16* aw1 = &As[1][wave * 8][0];
  u16* aw2 = &As[2][wave * 8][0];
  u16* bw0 = &Bs[0][wave * 8][0];
  u16* bw1 = &Bs[1][wave * 8][0];
  u16* bw2 = &Bs[2][wave * 8][0];

  int e7 = l16 & 7;
  int blk0 = ((quad) ^ e7) * 8, blk1 = ((4 + quad) ^ e7) * 8;
  const u16* aP0_0 = &As[0][wr * 64 + l16][0] + blk0;
  const u16* aP0_1 = &As[0][wr * 64 + l16][0] + blk1;
  const u16* aP1_0 = &As[1][wr * 64 + l16][0] + blk0;
  const u16* aP1_1 = &As[1][wr * 64 + l16][0] + blk1;
  const u16* aP2_0 = &As[2][wr * 64 + l16][0] + blk0;
  const u16* aP2_1 = &As[2][wr * 64 + l16][0] + blk1;
  const u16* bP0_0 = &Bs[0][wc * 64 + l16][0] + blk0;
  const u16* bP0_1 = &Bs[0][wc * 64 + l16][0] + blk1;
  const u16* bP1_0 = &Bs[1][wc * 64 + l16][0] + blk0;
  const u16* bP1_1 = &Bs[1][wc * 64 + l16][0] + blk1;
  const u16* bP2_0 = &Bs[2][wc * 64 + l16][0] + blk0;
  const u16* bP2_1 = &Bs[2][wc * 64 + l16][0] + blk1;

#define SBAR()                            \
  {                                       \
    asm volatile("" ::: "memory");        \
    __builtin_amdgcn_s_barrier();         \
    asm volatile("" ::: "memory");        \
  }

#define GLD(gp, lp)                                                \
  __builtin_amdgcn_global_load_lds(                                \
      (const __attribute__((address_space(1))) void*)(gp),         \
      (__attribute__((address_space(3))) void*)(lp), 16, 0, 0)

#define STG_ALL(KT, SB)                                            \
  {                                                                \
    size_t ko = (size_t)(KT) * 64;                                 \
    GLD(gb + ko, bw##SB);                                          \
    GLD(gb + (size_t)64 * K + ko, bw##SB + 4096);                  \
    GLD(gb + (size_t)128 * K + ko, bw##SB + 8192);                 \
    GLD(gb + (size_t)192 * K + ko, bw##SB + 12288);                \
    GLD(ga + ko, aw##SB);                                          \
    GLD(ga + (size_t)64 * K + ko, aw##SB + 4096);                  \
  }

#define VM6() asm volatile("s_waitcnt vmcnt(6)" ::: "memory")
#define VM0() asm volatile("s_waitcnt vmcnt(0)" ::: "memory")
#define VMNONE()

#define TILE(T, BUF, SB, DOSTAGE, WAITOP)                                     \
  {                                                                           \
    if (DOSTAGE) STG_ALL((T) + 2, SB);                                        \
    bf16x8 bf0[4], bf1[4], af0[4], af1[4];                                    \
    _Pragma("unroll") for (int n = 0; n < 4; ++n) {                           \
      bf0[n] = *(const bf16x8*)(bP##BUF##_0 + n * 1024);                      \
      bf1[n] = *(const bf16x8*)(bP##BUF##_1 + n * 1024);                      \
    }                                                                         \
    _Pragma("unroll") for (int m = 0; m < 4; ++m) {                           \
      af0[m] = *(const bf16x8*)(aP##BUF##_0 + m * 1024);                      \
      af1[m] = *(const bf16x8*)(aP##BUF##_1 + m * 1024);                      \
    }                                                                         \
    __builtin_amdgcn_s_setprio(1);                                            \
    _Pragma("unroll") for (int m = 0; m < 4; ++m)                             \
        _Pragma("unroll") for (int n = 0; n < 4; ++n) {                       \
      acc[m][n] = MFMA16(af0[m], bf0[n], acc[m][n]);                          \
      acc[m][n] = MFMA16(af1[m], bf1[n], acc[m][n]);                          \
    }                                                                         \
    __builtin_amdgcn_s_setprio(0);                                            \
    WAITOP();                                                                 \
    SBAR();                                                                   \
  }

  STG_ALL(0, 0);
  STG_ALL(1, 1);
  VM6();
  SBAR();

#pragma unroll 1
  for (int t3 = 0; t3 < 4; ++t3) {   // tiles 0..11
    int t = t3 * 3;
    TILE(t, 0, 2, 1, VM6);
    TILE(t + 1, 1, 0, 1, VM6);
    TILE(t + 2, 2, 1, 1, VM6);
  }
  TILE(12, 0, 2, 1, VM6);
  TILE(13, 1, 0, 1, VM6);
  TILE(14, 2, 1, 0, VM0);
  TILE(15, 0, 1, 0, VMNONE);

#undef TILE
#undef VMNONE
#undef VM0
#undef VM6
#undef STG_ALL
#undef GLD
#undef SBAR

#pragma unroll
  for (int m = 0; m < 4; ++m)
#pragma unroll
    for (int n = 0; n < 4; ++n)
#pragma unroll
      for (int r = 0; r < 4; ++r) {
        int row = bm + wr * 64 + m * 16 + quad * 4 + r;
        int col = bn + wc * 64 + n * 16 + l16;
        of[(size_t)row * DM + col] = acc[m][n][r] + b0[col];
      }
}

// ---------------- flash attention (R0 structure + XCD swizzle) ------------
// grid: (S/128, NH, BB). R18: adds the R2-verified XCD remap (FETCH
// 139->24.6 MB; KV L2-resident per XCD) to the otherwise R0-exact kernel —
// never previously tested without the MFMA-ones regression.
__global__ __launch_bounds__(256) void k_attn(const u16* __restrict__ Q,
                                              const u16* __restrict__ Kg,
                                              const u16* __restrict__ VT,
                                              u16* __restrict__ ctx) {
  __shared__ __align__(16) u16 Ks[2][64][64];
  __shared__ __align__(16) u16 Vts[2][64][64];  // [d][kv], swizzled
  int tid = threadIdx.x;
  int wave = tid >> 6, lane = tid & 63, quad = lane >> 4, l16 = lane & 15;
  // XCD remap: all 16 q-tiles of one (b,h) on one XCD (8 bh-groups x 512KB
  // = 4MB = its L2). Bijective: inverse xcd=bh>>3, iw=(bh&7)*16+qtile.
  int g = blockIdx.x + gridDim.x * (blockIdx.y + gridDim.y * blockIdx.z);
  int xcd = g & 7, iw = g >> 3;
  int bh = xcd * 8 + (iw >> 4);  // 0..63
  int qtile = iw & 15;
  int h = bh & 15, b = bh >> 4;
  int q0 = qtile * 128;
  size_t bhoff = ((size_t)b * NH + h) * SS * DH;
  const u16* Qp = Q + bhoff + (size_t)(q0 + wave * 32) * DH;
  const u16* Kp = Kg + bhoff;
  const u16* Vp = VT + ((size_t)b * NH + h) * DH * SS;  // [Dh][S]

  bf16x8 qf[2][2];
#pragma unroll
  for (int qt = 0; qt < 2; ++qt) {
    qf[qt][0] = ld_bf8(Qp + (qt * 16 + l16) * DH + quad * 8);
    qf[qt][1] = ld_bf8(Qp + (qt * 16 + l16) * DH + 32 + quad * 8);
  }

  f32x4 Ot[4][2] = {};           // [d-tile][q-tile], O^T C-layout
  float lrun[2] = {0.0f, 0.0f};  // per-lane partial sums (q = l16)

  int lrow = lane >> 3;            // 0..7 (row within 8-row DMA chunk)
  int lcb = (lane & 7) ^ lrow;     // swizzled global col-block
  const u16* kdma[2];
  const u16* vdma[2];
  u16* kl[2];
  u16* vl[2];
#pragma unroll
  for (int i = 0; i < 2; ++i) {
    int chunk = wave * 2 + i;      // 0..7, 8 rows each
    kdma[i] = Kp + (size_t)(chunk * 8 + lrow) * DH + lcb * 8;
    vdma[i] = Vp + (size_t)(chunk * 8 + lrow) * SS + lcb * 8;
    kl[i] = &Ks[0][chunk * 8][0];
    vl[i] = &Vts[0][chunk * 8][0];
  }

  int e7 = l16 & 7, qh = quad >> 1, qp = quad & 1;
  const u16* kfr0 = &Ks[0][l16][(quad ^ e7) * 8];        // d-blocks 0..3
  const u16* kfr1 = &Ks[0][l16][((quad + 4) ^ e7) * 8];  // d-blocks 4..7
  const u16* vfr[4];
#pragma unroll
  for (int c = 0; c < 4; ++c)
    vfr[c] = &Vts[0][l16][((2 * c + qh) ^ e7) * 8 + qp * 4];

#pragma unroll
  for (int i = 0; i < 2; ++i) {
    __builtin_amdgcn_global_load_lds(
        (const __attribute__((address_space(1))) void*)kdma[i],
        (__attribute__((address_space(3))) void*)kl[i], 16, 0, 0);
    __builtin_amdgcn_global_load_lds(
        (const __attribute__((address_space(1))) void*)vdma[i],
        (__attribute__((address_space(3))) void*)vl[i], 16, 0, 0);
  }
  __syncthreads();

  int kv = 64;  // next tile to stage

#define ATTN_STEP(P)                                                          \
  {                                                                           \
    f32x4 s[2][4];                                                            \
    _Pragma("unroll") for (int t = 0; t < 4; ++t) {                           \
      bf16x8 kb0 = *(const bf16x8*)(kfr0 + (P) * 4096 + t * 1024);            \
      bf16x8 kb1 = *(const bf16x8*)(kfr1 + (P) * 4096 + t * 1024);            \
      _Pragma("unroll") for (int qt = 0; qt < 2; ++qt) {                      \
        f32x4 z = {};                                                         \
        z = MFMA16(kb0, qf[qt][0], z);                                        \
        z = MFMA16(kb1, qf[qt][1], z);                                        \
        s[qt][t] = z;                                                         \
      }                                                                       \
    }                                                                         \
    if (kv < SS) {                                                            \
      _Pragma("unroll") for (int i = 0; i < 2; ++i) {                         \
        __builtin_amdgcn_global_load_lds(                                     \
            (const __attribute__((address_space(1))) void*)(kdma[i] +         \
                                                            (size_t)kv * DH), \
            (__attribute__((address_space(3))) void*)(kl[i] +                 \
                                                      (1 - (P)) * 4096),      \
            16, 0, 0);                                                        \
        __builtin_amdgcn_global_load_lds(                                     \
            (const __attribute__((address_space(1))) void*)(vdma[i] + kv),    \
            (__attribute__((address_space(3))) void*)(vl[i] +                 \
                                                      (1 - (P)) * 4096),      \
            16, 0, 0);                                                        \
      }                                                                       \
    }                                                                         \
    bf16x4 pb[2][4];                                                          \
    _Pragma("unroll") for (int qt = 0; qt < 2; ++qt)                          \
        _Pragma("unroll") for (int t = 0; t < 4; ++t) {                       \
      unsigned u0 = __builtin_bit_cast(                                       \
          unsigned, __builtin_amdgcn_exp2f(s[qt][t][0]));                     \
      unsigned u1 = __builtin_bit_cast(                                       \
          unsigned, __builtin_amdgcn_exp2f(s[qt][t][1]));                     \
      unsigned u2 = __builtin_bit_cast(                                       \
          unsigned, __builtin_amdgcn_exp2f(s[qt][t][2]));                     \
      unsigned u3 = __builtin_bit_cast(                                       \
          unsigned, __builtin_amdgcn_exp2f(s[qt][t][3]));                     \
      unsigned w0 = __builtin_amdgcn_perm(u1, u0, 0x07060302u);               \
      unsigned w1 = __builtin_amdgcn_perm(u3, u2, 0x07060302u);               \
      lrun[qt] += __builtin_bit_cast(float, w0 << 16) +                       \
                  __builtin_bit_cast(float, w0 & 0xffff0000u) +               \
                  __builtin_bit_cast(float, w1 << 16) +                       \
                  __builtin_bit_cast(float, w1 & 0xffff0000u);                \
      uintx2 w;                                                               \
      w[0] = w0;                                                              \
      w[1] = w1;                                                              \
      pb[qt][t] = __builtin_bit_cast(bf16x4, w);                              \
    }                                                                         \
    _Pragma("unroll") for (int c = 0; c < 4; ++c)                             \
        _Pragma("unroll") for (int dt = 0; dt < 4; ++dt) {                    \
      bf16x4 va = *(const bf16x4*)(vfr[c] + (P) * 4096 + dt * 1024);          \
      _Pragma("unroll") for (int qt = 0; qt < 2; ++qt)                        \
          Ot[dt][qt] = MFMA16K16(va, pb[qt][c], Ot[dt][qt]);                  \
    }                                                                         \
    __syncthreads();                                                          \
    kv += 64;                                                                 \
  }

  for (int it = 0; it < SS / 128; ++it) {
    ATTN_STEP(0);
    ATTN_STEP(1);
  }
#undef ATTN_STEP

  float inv[2];
#pragma unroll
  for (int qt = 0; qt < 2; ++qt) {
    float l = lrun[qt];
    l += __shfl_xor(l, 16);
    l += __shfl_xor(l, 32);
    inv[qt] = 1.0f / l;
  }

#pragma unroll
  for (int qt = 0; qt < 2; ++qt) {
    int q = q0 + wave * 32 + qt * 16 + l16;
    size_t ob = ((size_t)b * SS + q) * DM + h * DH;
#pragma unroll
    for (int dt = 0; dt < 4; ++dt) {
      uintx2 o;
      o[0] = pack2bf(Ot[dt][qt][0] * inv[qt], Ot[dt][qt][1] * inv[qt]);
      o[1] = pack2bf(Ot[dt][qt][2] * inv[qt], Ot[dt][qt][3] * inv[qt]);
      *(uintx2*)(&ctx[ob + dt * 16 + quad * 4]) = o;
    }
  }
}

extern "C" void kernel_launch(void* const* d_in, const int* in_sizes, int n_in,
                              void* d_out, int out_size, void* d_ws, size_t ws_size,
                              hipStream_t stream) {
  const float* x  = (const float*)d_in[0];
  const float* Wq = (const float*)d_in[1];
  const float* bq = (const float*)d_in[2];
  const float* Wk = (const float*)d_in[3];
  const float* bk = (const float*)d_in[4];
  const float* Wv = (const float*)d_in[5];
  const float* bv = (const float*)d_in[6];
  const float* Wo = (const float*)d_in[7];
  const float* bo = (const float*)d_in[8];
  float* out = (float*)d_out;

  char* ws = (char*)d_ws;
  u16* xb = (u16*)(ws);                        // 16 MB  [8192,1024] bf16
  u16* Wt = (u16*)(ws + (16u << 20));          //  8 MB  [4096,1024] bf16
  u16* Qb = (u16*)(ws + (24u << 20));          // 16 MB  [B,H,S,Dh] (pre-scaled)
  u16* Kb = (u16*)(ws + (40u << 20));          // 16 MB  [B,H,S,Dh]
  u16* VT = (u16*)(ws + (56u << 20));          // 16 MB  [B,H,Dh,S]
  u16* Cb = (u16*)(ws + (72u << 20));          // 16 MB  [B,S,D] bf16 ctx

  k_prep<<<8192 + 1024, 256, 0, stream>>>(x, xb, Wq, Wk, Wv, Wo, Wt);
  k_gemm3<<<dim3(64, 12), 512, 0, stream>>>(
      xb, Wt, bq, bk, bv, Qb, Kb, VT);
  k_attn<<<dim3(SS / 128, NH, BB), 256, 0, stream>>>(Qb, Kb, VT, Cb);
  k_gemmo<<<dim3(64, 4), 512, 0, stream>>>(
      Cb, Wt + (size_t)3 * DM * DM, bo, out);
}